// Round 11
// baseline (414.358 us; speedup 1.0000x reference)
//
#include <hip/hip_runtime.h>

#define L_SEQ   2048
#define BATCH   2
#define NDIM    1024
#define NHEADS  16
#define HD      64
#define DSTATE  16
#define DCONV   4
#define DINNER  2048
#define DTRANK  64
#define CHUNK   32
#define NCHUNK  (L_SEQ / CHUNK)   // 64
#define SPLIT_KT 8                // KV tiles per attention split
#define LOG2E   1.4426950408889634f

typedef short  short8  __attribute__((ext_vector_type(8)));
typedef float  floatx4 __attribute__((ext_vector_type(4)));

#define AS1 __attribute__((address_space(1)))
#define AS3 __attribute__((address_space(3)))

__device__ __forceinline__ float bf2f(ushort u) {
    union { uint i; float f; } v; v.i = ((uint)u) << 16; return v.f;
}
// bf16 convert: native v_cvt_pk_bf16_f32 (RNE, 1 VALU op) when available;
// manual RNE fallback (4 ops). [R13: manual f2bf was ~40% of flash VALU]
#if defined(__has_builtin) && __has_builtin(__builtin_amdgcn_cvt_pk_bf16_f32)
__device__ __forceinline__ ushort f2bf(float f) {
    auto p = __builtin_amdgcn_cvt_pk_bf16_f32(f, f);
    union { decltype(p) v; ushort u[2]; } cv; cv.v = p;
    return cv.u[0];
}
__device__ __forceinline__ uint pk2bf(float lo, float hi) {
    auto p = __builtin_amdgcn_cvt_pk_bf16_f32(lo, hi);
    union { decltype(p) v; uint u; } cv; cv.v = p;
    return cv.u;
}
#else
__device__ __forceinline__ ushort f2bf(float f) {
    uint x = __float_as_uint(f);
    uint r = (x + 0x7fffu + ((x >> 16) & 1u)) >> 16;
    return (ushort)r;
}
__device__ __forceinline__ uint pk2bf(float lo, float hi) {
    return ((uint)f2bf(hi) << 16) | (uint)f2bf(lo);
}
#endif
// raw v_exp_f32 (2^x); log2(e) pre-folded into operands.
#if defined(__has_builtin) && __has_builtin(__builtin_amdgcn_exp2f)
__device__ __forceinline__ float fast_exp2(float x) {
    return __builtin_amdgcn_exp2f(x);
}
#else
__device__ __forceinline__ float fast_exp2(float x) {
    return __expf(x * 0.6931471805599453f);
}
#endif
__device__ __forceinline__ float silu_f(float x) {
    return x / (1.f + __expf(-x));
}
__device__ __forceinline__ void gld_lds16(const void* g, void* l) {
    __builtin_amdgcn_global_load_lds((const AS1 uint*)g, (AS3 uint*)l, 16, 0, 0);
}
__device__ __forceinline__ float cvt_one(const void* s, int i, int f) {
    return f ? ((const float*)s)[i] : bf2f(((const ushort*)s)[i]);
}

// ---------------------------------------------------------------------------
// MEGA PREP: one launch: dtype-probe (per-block), x convert, 6 weight
// transposes, wxp pad, small-param f32 conversion.
// R21: Alog_f stores negA2 = -exp(A_log)*log2(e).
// R22: verifies A-structure into flag[1]; flag[1]==0 enables powers-of-w
// scan path (verified: scans out of top-5, total -26us).
// ---------------------------------------------------------------------------
__global__ __launch_bounds__(256) void prep_kernel(
    const void* __restrict__ x_raw,
    const void* __restrict__ wqkv, const void* __restrict__ wao,
    const void* __restrict__ win,  const void* __restrict__ wxp,
    const void* __restrict__ wdt,  const void* __restrict__ wout,
    const void* __restrict__ bqkv, const void* __restrict__ bao,
    const void* __restrict__ convw, const void* __restrict__ convb,
    const void* __restrict__ bdt,  const void* __restrict__ Alog,
    const void* __restrict__ Dp,
    ushort* __restrict__ x_b, ushort* __restrict__ wqkv_t,
    ushort* __restrict__ wao_t, ushort* __restrict__ win_t,
    ushort* __restrict__ wxp_t, ushort* __restrict__ wdt_t,
    ushort* __restrict__ wout_t,
    float* __restrict__ bqkv_f, float* __restrict__ bao_f,
    float* __restrict__ convw_f, float* __restrict__ convb_f,
    float* __restrict__ bdt_f, float* __restrict__ Alog_f,
    float* __restrict__ Dp_f, int* __restrict__ flag)
{
    __shared__ int cnt;
    __shared__ float tile[32][33];
    if (threadIdx.x == 0) cnt = 0;
    __syncthreads();
    {
        ushort w = ((const ushort*)x_raw)[threadIdx.x];
        int e = (w >> 7) & 0xff;
        if (w != 0 && (e < 100 || e > 140)) atomicAdd(&cnt, 1);
    }
    __syncthreads();
    const int f = (cnt >= 16) ? 1 : 0;
    if (blockIdx.x == 0 && threadIdx.x == 0) *flag = f;

    int id = blockIdx.x;
    if (id < 16384) {                               // x convert
        int i = id * 256 + threadIdx.x;
        x_b[i] = f2bf(cvt_one(x_raw, i, f));
        return;
    }
    id -= 16384;

    const void* src = nullptr; ushort* dst = nullptr; int K = 0, N = 0;
    if (id < 1152)                     { src = wqkv; dst = wqkv_t; K = 1024; N = 1152; }
    else if ((id -= 1152) < 1024)      { src = wao;  dst = wao_t;  K = 1024; N = 1024; }
    else if ((id -= 1024) < 4096)      { src = win;  dst = win_t;  K = 1024; N = 4096; }
    else if ((id -= 4096) < 192)       { src = wxp;  dst = wxp_t;  K = 2048; N = 96;   }
    else if ((id -= 192)  < 128)       { src = wdt;  dst = wdt_t;  K = 64;   N = 2048; }
    else if ((id -= 128)  < 2048)      { src = wout; dst = wout_t; K = 2048; N = 1024; }
    else {
        id -= 2048;
        if (id < 256) {                              // wxp pad rows 96..127
            wxp_t[(size_t)96 * DINNER + id * 256 + threadIdx.x] = 0;
        } else {                                     // small params
            int i = (id - 256) * 256 + threadIdx.x;
            if      (i < 1152)   bqkv_f[i]          = cvt_one(bqkv,  i,          f);
            else if (i < 2176)   bao_f[i - 1152]    = cvt_one(bao,   i - 1152,   f);
            else if (i < 10368)  convw_f[i - 2176]  = cvt_one(convw, i - 2176,   f);
            else if (i < 12416)  convb_f[i - 10368] = cvt_one(convb, i - 10368,  f);
            else if (i < 14464)  bdt_f[i - 12416]   = cvt_one(bdt,   i - 12416,  f);
            else if (i < 47232) {
                int ai = i - 14464;
                float v = -__expf(cvt_one(Alog, ai, f)) * LOG2E;   // negA2
                Alog_f[ai] = v;
                int np1 = (ai & 15) + 1;
                float expv = -(float)np1 * LOG2E;
                if (fabsf(v - expv) > 1e-5f * (float)np1)
                    atomicAdd(flag + 1, 1);
            }
            else if (i < 49280)  Dp_f[i - 47232]    = cvt_one(Dp,    i - 47232,  f);
        }
        return;
    }

    const int ntn = N / 32;
    const int n0 = (id % ntn) * 32, k0 = (id / ntn) * 32;
    const int tx = threadIdx.x & 31, ty = threadIdx.x >> 5;
    #pragma unroll
    for (int r = 0; r < 4; ++r) {
        size_t o = (size_t)(k0 + ty + r * 8) * N + n0 + tx;
        tile[ty + r * 8][tx] = cvt_one(src, (int)o, f);
    }
    __syncthreads();
    #pragma unroll
    for (int r = 0; r < 4; ++r) {
        int n = n0 + ty + r * 8;
        dst[(size_t)n * K + k0 + tx] = f2bf(tile[tx][ty + r * 8]);
    }
}

// ---------------------------------------------------------------------------
// MFMA GEMM: 128x128 tile, BK=64, XOR k-slot swizzle.
// R17: bijective XCD swizzle (T1) + LDS-staged f32 epilogue.
// R19: T3-minimum 2-phase double-buffered staging.
// ---------------------------------------------------------------------------
__global__ __launch_bounds__(256) void gemm128(
    const ushort* __restrict__ A, int lda,
    const ushort* __restrict__ Wt,
    const float* __restrict__ bias,
    const ushort* __restrict__ resb,
    ushort* __restrict__ outb, float* __restrict__ outf,
    const int* __restrict__ dtflag,
    int N, int K, int act, int klen, float* __restrict__ psum, int swap)
{
    __shared__ __align__(16) char smem[65536];   // 2 x (As 16K + Bs 16K)

    const int tid  = threadIdx.x;
    const int wave = tid >> 6;
    const int lane = tid & 63;
    const int wm = (wave >> 1) * 64;
    const int wn = (wave & 1) * 64;
    const int fm = lane & 15;
    const int quad = lane >> 4;

    // T1 bijective XCD swizzle (nwg % 8 == 0 at every call site)
    int bx = blockIdx.x, by = blockIdx.y;
    {
        const int gx = gridDim.x;
        const int nwg = gx * gridDim.y;
        const int id = by * gx + bx;
        const int qq = nwg >> 3;
        const int sid = (id & 7) * qq + (id >> 3);
        bx = sid % gx; by = sid / gx;
    }
    const int m0 = (swap ? bx : by) * 128;
    const int n0 = (swap ? by : bx) * 128;

    floatx4 acc[4][4];
    #pragma unroll
    for (int i = 0; i < 4; ++i)
        #pragma unroll
        for (int j = 0; j < 4; ++j) acc[i][j] = (floatx4){0.f, 0.f, 0.f, 0.f};

    int rowv[4], kgv[4];
    #pragma unroll
    for (int j = 0; j < 4; ++j) {
        int c = wave * 256 + j * 64 + lane;
        rowv[j] = c >> 3;
        kgv[j]  = (((c & 7) ^ ((c >> 3) & 7))) * 8;
    }

    const int kbeg = psum ? (blockIdx.z * klen) : 0;
    const int kend = kbeg + klen;

    auto stage = [&](int buf, int k0) {
        ushort* As = (ushort*)(smem + buf * 32768);
        ushort* Bs = (ushort*)(smem + buf * 32768 + 16384);
        #pragma unroll
        for (int j = 0; j < 4; ++j)
            gld_lds16(A  + (size_t)(m0 + rowv[j]) * lda + k0 + kgv[j],
                      &As[(wave * 256 + j * 64) * 8]);
        #pragma unroll
        for (int j = 0; j < 4; ++j)
            gld_lds16(Wt + (size_t)(n0 + rowv[j]) * K   + k0 + kgv[j],
                      &Bs[(wave * 256 + j * 64) * 8]);
    };

    // prologue: fill buffer 0, drain, sync
    stage(0, kbeg);
    __syncthreads();

    int cur = 0;
    for (int k0 = kbeg; k0 < kend; k0 += 64) {
        if (k0 + 64 < kend) stage(cur ^ 1, k0 + 64);   // overlap with compute
        const ushort* As = (const ushort*)(smem + cur * 32768);
        const ushort* Bs = (const ushort*)(smem + cur * 32768 + 16384);

        #pragma unroll
        for (int h = 0; h < 2; ++h) {
            short8 af[4], bf[4];
            #pragma unroll
            for (int i = 0; i < 4; ++i) {
                int row = wm + i * 16 + fm;
                int slot = (h * 4 + quad) ^ (row & 7);
                af[i] = *(const short8*)&As[row * 64 + slot * 8];
            }
            #pragma unroll
            for (int j = 0; j < 4; ++j) {
                int row = wn + j * 16 + fm;
                int slot = (h * 4 + quad) ^ (row & 7);
                bf[j] = *(const short8*)&Bs[row * 64 + slot * 8];
            }
            #pragma unroll
            for (int i = 0; i < 4; ++i)
                #pragma unroll
                for (int j = 0; j < 4; ++j)
                    acc[i][j] = __builtin_amdgcn_mfma_f32_16x16x32_bf16(af[i], bf[j], acc[i][j], 0, 0, 0);
        }
        __syncthreads();   // drains next-tile stage + syncs buffer handoff
        cur ^= 1;
    }

    if (psum) {
        int mgrid = swap ? gridDim.x : gridDim.y;
        float* po = psum + (size_t)blockIdx.z * ((size_t)mgrid * 128) * N;
        #pragma unroll
        for (int j = 0; j < 4; ++j) {
            int col = n0 + wn + j * 16 + fm;
            #pragma unroll
            for (int i = 0; i < 4; ++i) {
                int rowb = m0 + wm + i * 16 + quad * 4;
                #pragma unroll
                for (int r = 0; r < 4; ++r)
                    po[(size_t)(rowb + r) * N + col] = acc[i][j][r];
            }
        }
        return;
    }

    // ---- R17 staged epilogue: f32 through LDS, coalesced stores ----
    const int flagv = dtflag ? *dtflag : 0;
    const bool wf = dtflag ? (flagv != 0) : (outf != nullptr);
    float* Cs = (float*)smem;               // [64][132] f32 = 33792 B (aliases bufs)
    const int lrw = (wm >> 1) + quad * 4;   // + ih*16 + r
    #pragma unroll
    for (int p = 0; p < 2; ++p) {
        #pragma unroll
        for (int ih = 0; ih < 2; ++ih) {
            const int i = 2 * p + ih;
            #pragma unroll
            for (int j = 0; j < 4; ++j) {
                float bvv = bias ? bias[n0 + wn + j * 16 + fm] : 0.f;
                #pragma unroll
                for (int r = 0; r < 4; ++r) {
                    float v = acc[i][j][r] + bvv;
                    if (act == 1)
                        v = fmaxf(v, 0.f) + __logf(1.f + __expf(-fabsf(v)));
                    Cs[(lrw + ih * 16 + r) * 132 + wn + j * 16 + fm] = v;
                }
            }
        }
        __syncthreads();
        #pragma unroll
        for (int g = 0; g < 4; ++g) {
            const int lr   = g * 16 + (tid >> 4);
            const int colc = (tid & 15) * 8;
            const int grow = m0 + (lr >> 5) * 64 + (2 * p + ((lr >> 4) & 1)) * 16 + (lr & 15);
            const size_t o = (size_t)grow * N + n0 + colc;
            floatx4 v0 = *(const floatx4*)&Cs[lr * 132 + colc];
            floatx4 v1 = *(const floatx4*)&Cs[lr * 132 + colc + 4];
            float vv[8] = {v0[0], v0[1], v0[2], v0[3], v1[0], v1[1], v1[2], v1[3]};
            if (resb) {
                short8 rs = *(const short8*)&resb[o];
                #pragma unroll
                for (int k = 0; k < 8; ++k) vv[k] += bf2f((ushort)rs[k]);
            }
            if (wf) {
                *(floatx4*)&outf[o]     = (floatx4){vv[0], vv[1], vv[2], vv[3]};
                *(floatx4*)&outf[o + 4] = (floatx4){vv[4], vv[5], vv[6], vv[7]};
            } else {
                short8 ov;
                #pragma unroll
                for (int k = 0; k < 8; ++k) ov[k] = (short)f2bf(vv[k]);
                *(short8*)&outb[o] = ov;
            }
        }
        __syncthreads();
    }
}

// ---------------------------------------------------------------------------
// combine split-K partials (4096 x 128 padded) -> xdbl bf16 (stride 96).
// ---------------------------------------------------------------------------
__global__ __launch_bounds__(256) void combine_xdbl(
    const float* __restrict__ psum, ushort* __restrict__ xdbl)
{
    int idx = blockIdx.x * 256 + threadIdx.x;
    int row = idx / 96, col = idx - row * 96;
    float s = 0.f;
    #pragma unroll
    for (int z = 0; z < 8; ++z)
        s += psum[(size_t)z * 4096 * 128 + row * 128 + col];
    xdbl[idx] = f2bf(s);
}

// ---------------------------------------------------------------------------
// Flash MQA attention, split-KV, static-max softmax.
// R16: swapped QK^T (T12) + in-register bpermute P exchange.
// R18: dense LPT 1D grid.
// R23 LDS-PIPE ATTACK (counters: 47us, VALUBusy 48, MfmaUtil 14,
// BANK_CONFLICT 4.3M; per-iter cost ~6100cy >> ~1500cy dep chain ->
// LDS pipe saturated by the Vt transpose scatter: 4096 scalar
// ds_write_b16 per block-iter):
//   (a) V staged LINEARLY: 2x ds_write_b128/thread into Vs[64][64],
//       XOR-swizzled d' = d ^ (((row>>3)&3)<<4) so PV column reads are
//       conflict-free (4 quads -> 4 distinct 8-bank octets, 2-way only).
//       PV B-fragments via 8x ds_read_u16 each. DS ops/iter: ~4100 -> ~800.
//   (b) K/V double-buffered (34.8KB, 4 blocks/CU): stage(next) +
//       prefetch(next-next) before compute(cur); ONE barrier per iter.
// ---------------------------------------------------------------------------
__global__ __launch_bounds__(256) void flash_attn_split(
    const ushort* __restrict__ qkv, ushort* __restrict__ att,
    ushort* __restrict__ partO, float* __restrict__ partL)
{
    __shared__ __align__(16) ushort Ks[2][64 * 72];
    __shared__ __align__(16) ushort Vs[2][64 * 64];

    // ---- R18 dense LPT decode ----
    const int id  = blockIdx.x;
    const int e   = id >> 3;
    const int hgb = id & 7;
    const int hg  = hgb >> 1;
    const int b   = hgb & 1;
    int tile, s;
    if (e < 104) {
        if      (e < 50)  { s = 0; tile = 63 - e; }
        else if (e < 84)  { s = 1; tile = 63 - (e - 50); }
        else if (e < 102) { s = 2; tile = 63 - (e - 84); }
        else              { s = 3; tile = 63 - (e - 102); }
    } else {
        const int rem = e - 104;
        const int w   = 7 - (rem >> 3);
        s    = (rem & 7) >> 1;
        tile = 2 * (8 * s + w) - 2 + (rem & 1);
    }

    const int q0 = tile * 32;
    const int nkv = (q0 >> 6) + 1;
    const int nsplit = (nkv + SPLIT_KT - 1) / SPLIT_KT;
    const int kt0 = s * SPLIT_KT;
    const int kt1 = (nkv < kt0 + SPLIT_KT) ? nkv : (kt0 + SPLIT_KT);

    const int tid  = threadIdx.x;
    const int wave = tid >> 6;
    const int lane = tid & 63;
    const int fm   = lane & 15;
    const int quad = lane >> 4;
    const int h    = hg * 4 + wave;

    const int srow = tid >> 3;
    const int scol = (tid & 7) * 8;

    // bpermute byte-addresses for the P^T -> A-fragment exchange
    const int addrA = (fm + (quad & 1) * 32) * 4;
    const int addrB = addrA + 64;
    const bool jlo_sel = (quad < 2);

    short8 qf[2][2];
    #pragma unroll
    for (int i = 0; i < 2; ++i)
        #pragma unroll
        for (int kh = 0; kh < 2; ++kh)
            qf[i][kh] = *(const short8*)(qkv +
                (size_t)(b * L_SEQ + q0 + i * 16 + fm) * 1152 + h * HD + kh * 32 + quad * 8);

    floatx4 acc[2][4];
    float l_lane[2];
    #pragma unroll
    for (int i = 0; i < 2; ++i) {
        #pragma unroll
        for (int j = 0; j < 4; ++j) acc[i][j] = (floatx4){0.f, 0.f, 0.f, 0.f};
        l_lane[i] = 0.f;
    }

    short8 kreg[2], vreg[2];
    auto loadkv = [&](int kt_) {
        const int kv0n = kt_ * 64;
        #pragma unroll
        for (int pass = 0; pass < 2; ++pass) {
            int row = srow + pass * 32;
            const ushort* kp = qkv + (size_t)(b * L_SEQ + kv0n + row) * 1152 + NDIM + scol;
            kreg[pass] = *(const short8*)kp;
            vreg[pass] = *(const short8*)(kp + HD);
        }
    };
    auto stagebuf = [&](int bufi) {
        #pragma unroll
        for (int pass = 0; pass < 2; ++pass) {
            int row = srow + pass * 32;
            *(short8*)&Ks[bufi][row * 72 + scol] = kreg[pass];
            int sc2 = scol ^ (((row >> 3) & 3) << 4);
            *(short8*)&Vs[bufi][row * 64 + sc2] = vreg[pass];
        }
    };

    // prologue: stage kt0 into buf0, prefetch kt0+1 into regs
    loadkv(kt0);
    stagebuf(0);
    if (kt0 + 1 < kt1) loadkv(kt0 + 1);
    __syncthreads();

    int cur = 0;
    for (int kt = kt0; kt < kt1; ++kt) {
        const int kv0 = kt * 64;
        // stage next tile into other buffer; prefetch tile after that
        if (kt + 1 < kt1) stagebuf(cur ^ 1);
        if (kt + 2 < kt1) loadkv(kt + 2);

        // QK^T swapped: spT[j][i] = S^T, lane holds (kv=j*16+quad*4+r, q=i*16+fm)
        floatx4 spT[4][2];
        __builtin_amdgcn_s_setprio(1);
        #pragma unroll
        for (int j = 0; j < 4; ++j) {
            short8 kf0 = *(const short8*)&Ks[cur][(j * 16 + fm) * 72 + quad * 8];
            short8 kf1 = *(const short8*)&Ks[cur][(j * 16 + fm) * 72 + 32 + quad * 8];
            #pragma unroll
            for (int i = 0; i < 2; ++i) {
                floatx4 z = (floatx4){0.f, 0.f, 0.f, 0.f};
                z = __builtin_amdgcn_mfma_f32_16x16x32_bf16(kf0, qf[i][0], z, 0, 0, 0);
                z = __builtin_amdgcn_mfma_f32_16x16x32_bf16(kf1, qf[i][1], z, 0, 0, 0);
                spT[j][i] = z;
            }
        }
        __builtin_amdgcn_s_setprio(0);

        const bool diag = (kt == nkv - 1);
        #pragma unroll
        for (int j = 0; j < 4; ++j)
            #pragma unroll
            for (int i = 0; i < 2; ++i) {
                #pragma unroll
                for (int r = 0; r < 4; ++r) {
                    float p = fast_exp2(spT[j][i][r] * 0.18033688011112042f);  // 0.125*log2e
                    if (diag) {
                        int kvg = kv0 + j * 16 + quad * 4 + r;
                        int qg  = q0 + i * 16 + fm;
                        if (kvg > qg) p = 0.f;
                    }
                    spT[j][i][r] = p;
                    l_lane[i] += p;
                }
            }

        // pack to bf16 dwords: w0 = kv pair (r0,r1), w1 = (r2,r3)
        uint w0[4][2], w1[4][2];
        #pragma unroll
        for (int j = 0; j < 4; ++j)
            #pragma unroll
            for (int i = 0; i < 2; ++i) {
                w0[j][i] = pk2bf(spT[j][i][0], spT[j][i][1]);
                w1[j][i] = pk2bf(spT[j][i][2], spT[j][i][3]);
            }

        // in-register P^T -> PV A-fragment via ds_bpermute (no LDS buffer)
        short8 pf[2][2];
        #pragma unroll
        for (int i = 0; i < 2; ++i)
            #pragma unroll
            for (int kh = 0; kh < 2; ++kh) {
                const int jl = kh * 2, jh = kh * 2 + 1;
                uint a0 = (uint)__builtin_amdgcn_ds_bpermute(addrA, (int)w0[jl][i]);
                uint a1 = (uint)__builtin_amdgcn_ds_bpermute(addrA, (int)w0[jh][i]);
                uint b0 = (uint)__builtin_amdgcn_ds_bpermute(addrA, (int)w1[jl][i]);
                uint b1 = (uint)__builtin_amdgcn_ds_bpermute(addrA, (int)w1[jh][i]);
                uint c0 = (uint)__builtin_amdgcn_ds_bpermute(addrB, (int)w0[jl][i]);
                uint c1 = (uint)__builtin_amdgcn_ds_bpermute(addrB, (int)w0[jh][i]);
                uint d0 = (uint)__builtin_amdgcn_ds_bpermute(addrB, (int)w1[jl][i]);
                uint d1 = (uint)__builtin_amdgcn_ds_bpermute(addrB, (int)w1[jh][i]);
                union { uint u[4]; short8 s; } cv;
                cv.u[0] = jlo_sel ? a0 : a1;
                cv.u[1] = jlo_sel ? b0 : b1;
                cv.u[2] = jlo_sel ? c0 : c1;
                cv.u[3] = jlo_sel ? d0 : d1;
                pf[i][kh] = cv.s;
            }

        // PV: B-fragments from linear+swizzled Vs via scalar column reads.
        // dx = (dj*16+fm) ^ (quad<<4): for kv row r, stored col = d ^
        // (((r>>3)&3)<<4); with r = kh*32+quad*8+e, ((r>>3)&3) == quad.
        __builtin_amdgcn_s_setprio(1);
        #pragma unroll
        for (int dj = 0; dj < 4; ++dj) {
            const int dx = (dj * 16 + fm) ^ (quad << 4);
            ushort t0[8], t1[8];
            #pragma unroll
            for (int e2 = 0; e2 < 8; ++e2) {
                t0[e2] = Vs[cur][(quad * 8 + e2) * 64 + dx];
                t1[e2] = Vs[cur][(32 + quad * 8 + e2) * 64 + dx];
            }
            short8 vf0 = *(short8*)t0;
            short8 vf1 = *(short8*)t1;
            #pragma unroll
            for (int i = 0; i < 2; ++i) {
                acc[i][dj] = __builtin_amdgcn_mfma_f32_16x16x32_bf16(pf[i][0], vf0, acc[i][dj], 0, 0, 0);
                acc[i][dj] = __builtin_amdgcn_mfma_f32_16x16x32_bf16(pf[i][1], vf1, acc[i][dj], 0, 0, 0);
            }
        }
        __builtin_amdgcn_s_setprio(0);

        __syncthreads();   // next tile staged + this tile's reads done
        cur ^= 1;
    }

    // reduce l across the 4 quads (kv partial sums); all lanes then hold
    // the full row-sum for q = i*16+fm
    #pragma unroll
    for (int i = 0; i < 2; ++i) {
        float rs = l_lane[i];
        rs += __shfl_xor(rs, 16);
        rs += __shfl_xor(rs, 32);
        l_lane[i] = rs;
    }

    if (nsplit == 1) {
        #pragma unroll
        for (int i = 0; i < 2; ++i) {
            float inv[4];
            #pragma unroll
            for (int r = 0; r < 4; ++r)
                inv[r] = 1.f / __shfl(l_lane[i], quad * 4 + r, 16);
            #pragma unroll
            for (int dj = 0; dj < 4; ++dj)
                #pragma unroll
                for (int r = 0; r < 4; ++r) {
                    int q = q0 + i * 16 + quad * 4 + r;
                    att[(size_t)(b * L_SEQ + q) * NDIM + h * HD + dj * 16 + fm] =
                        f2bf(acc[i][dj][r] * inv[r]);
                }
        }
    } else {
        size_t pbase = ((size_t)((s * 2 + b) * 16 + h)) * L_SEQ;
        #pragma unroll
        for (int i = 0; i < 2; ++i)
            #pragma unroll
            for (int dj = 0; dj < 4; ++dj)
                #pragma unroll
                for (int r = 0; r < 4; ++r) {
                    int q = q0 + i * 16 + quad * 4 + r;
                    partO[(pbase + q) * 64 + dj * 16 + fm] = f2bf(acc[i][dj][r]);
                }
        if (lane < 16) {
            #pragma unroll
            for (int i = 0; i < 2; ++i)
                partL[pbase + q0 + i * 16 + fm] = l_lane[i];
        }
    }
}

// ---------------------------------------------------------------------------
// combine attention split partials for q >= 512.
// ---------------------------------------------------------------------------
__global__ __launch_bounds__(256) void attn_combine(
    const ushort* __restrict__ partO, const float* __restrict__ partL,
    ushort* __restrict__ att)
{
    int gid = blockIdx.x * 256 + threadIdx.x;
    int t8 = gid & 7;
    int row = gid >> 3;
    int q  = 512 + (row % 1536);
    int bh = row / 1536;
    int b = bh >> 4, h = bh & 15;
    int nsplit = (((q >> 5) >> 1) + 1 + SPLIT_KT - 1) / SPLIT_KT;

    float sum[8] = {0.f, 0.f, 0.f, 0.f, 0.f, 0.f, 0.f, 0.f};
    float L = 0.f;
    for (int s = 0; s < nsplit; ++s) {
        size_t pbase = ((size_t)((s * 2 + b) * 16 + h)) * L_SEQ + q;
        L += partL[pbase];
        short8 o = *(const short8*)&partO[pbase * 64 + t8 * 8];
        #pragma unroll
        for (int k = 0; k < 8; ++k) sum[k] += bf2f((ushort)o[k]);
    }
    float inv = 1.f / L;
    short8 outv;
    #pragma unroll
    for (int k = 0; k < 8; ++k) outv[k] = (short)f2bf(sum[k] * inv);
    *(short8*)&att[((size_t)(b * L_SEQ + q)) * NDIM + h * HD + t8 * 8] = outv;
}

// ---------------------------------------------------------------------------
// depthwise conv (window 4, left pad 3) + bias + silu.
// R15: 1 channel/thread, 16 L-positions/thread — coalesced weights+acts.
// ---------------------------------------------------------------------------
__global__ __launch_bounds__(256) void conv_silu(
    const ushort* __restrict__ xr, const float* __restrict__ conv_w,
    const float* __restrict__ conv_b, ushort* __restrict__ u)
{
    const int c   = ((blockIdx.x & 7) << 8) + threadIdx.x;  // 0..2047
    const int bl0 = (blockIdx.x >> 3) << 4;                 // 0..4080 step 16
    const int l0  = bl0 & (L_SEQ - 1);                      // pos within batch

    const floatx4 wv = *(const floatx4*)&conv_w[c * DCONV];
    const float bias = conv_b[c];

    float xv[19];
    #pragma unroll
    for (int t = 0; t < 19; ++t) {
        int ls = l0 - 3 + t;
        xv[t] = (ls >= 0)
              ? bf2f(xr[(size_t)(bl0 - 3 + t) * (2 * DINNER) + c])
              : 0.f;
    }

    #pragma unroll
    for (int t = 0; t < 16; ++t) {
        float a = bias + xv[t] * wv[0] + xv[t + 1] * wv[1]
                       + xv[t + 2] * wv[2] + xv[t + 3] * wv[3];
        u[(size_t)(bl0 + t) * DINNER + c] = f2bf(silu_f(a));
    }
}

// ---------------------------------------------------------------------------
// Chunked selective scan, phase 1.  negA2 = -exp(A_log)*log2e (prep).
// R20 half-split kept. R22: structured powers-of-w path (verified).
// ---------------------------------------------------------------------------
__global__ __launch_bounds__(256) void scan_phase1(
    const ushort* __restrict__ delta, const ushort* __restrict__ u,
    const ushort* __restrict__ xdbl, const float* __restrict__ negA,
    float* __restrict__ Hend, float* __restrict__ Sdt,
    const int* __restrict__ sflag)
{
    const int idx  = blockIdx.x * 256 + threadIdx.x;
    const int lane = idx & 63;
    const int g    = idx >> 6;
    const int half = lane >> 5;                       // 0: n 0-7, 1: n 8-15
    const int d    = ((g & 63) << 5) + (lane & 31);
    const int b    = (g >> 6) & (BATCH - 1);
    const int c    = g >> 7;
    const int strA = (sflag[1] == 0);

    float h[8];
    #pragma unroll
    for (int n = 0; n < 8; ++n) h[n] = 0.f;

    const int t0 = c * CHUNK;
    size_t bd = ((size_t)b * L_SEQ + t0) * DINNER + d;
    size_t bx = ((size_t)b * L_SEQ + t0) * 96 + DTRANK + half * 8;
    float sdt = 0.f;

    if (strA) {
        for (int t = 0; t < CHUNK; ++t) {
            float dt = bf2f(delta[bd]);
            float uv = bf2f(u[bd]);
            sdt += dt;
            float du = dt * uv;
            short8 B0 = *(const short8*)&xdbl[bx];
            float w  = fast_exp2(-dt * LOG2E);        // exp(-dt)
            float w2 = w * w, w4 = w2 * w2, w8 = w4 * w4;
            float p3 = w2 * w;
            float q[8] = {w, w2, p3, w4, w4 * w, w4 * w2, w4 * p3, w8};
            float sc = half ? w8 : 1.f;
            #pragma unroll
            for (int n = 0; n < 8; ++n)
                h[n] = (q[n] * sc) * h[n] + du * bf2f((ushort)B0[n]);
            bd += DINNER; bx += 96;
        }
    } else {
        float Av[8];
        #pragma unroll
        for (int n = 0; n < 8; ++n)
            Av[n] = negA[d * DSTATE + half * 8 + n];
        for (int t = 0; t < CHUNK; ++t) {
            float dt = bf2f(delta[bd]);
            float uv = bf2f(u[bd]);
            sdt += dt;
            float du = dt * uv;
            short8 B0 = *(const short8*)&xdbl[bx];
            #pragma unroll
            for (int n = 0; n < 8; ++n)
                h[n] = fast_exp2(dt * Av[n]) * h[n] + du * bf2f((ushort)B0[n]);
            bd += DINNER; bx += 96;
        }
    }

    size_t ho = (((size_t)c * BATCH + b) * DINNER + d) * DSTATE + half * 8;
    *(floatx4*)&Hend[ho]     = (floatx4){h[0], h[1], h[2], h[3]};
    *(floatx4*)&Hend[ho + 4] = (floatx4){h[4], h[5], h[6], h[7]};
    if (half == 0)
        Sdt[((size_t)c * BATCH + b) * DINNER + d] = sdt;
}

// ---------------------------------------------------------------------------
// phase 2: in-place exclusive combine over 64 chunks.
// R19: batched 8-wide load/exp prefetch.
// ---------------------------------------------------------------------------
__global__ __launch_bounds__(256) void scan_phase2(
    float* __restrict__ H, const float* __restrict__ Sdt,
    const float* __restrict__ negA)
{
    const int idx = blockIdx.x * 256 + threadIdx.x;
    const int n = idx & (DSTATE - 1);
    const int d = (idx >> 4) & (DINNER - 1);
    const int b = idx >> 15;

    const float Av = negA[d * DSTATE + n];
    const size_t hstride = (size_t)BATCH * DINNER * DSTATE;
    const size_t sstride = (size_t)BATCH * DINNER;
    const size_t ho0 = ((size_t)b * DINNER + d) * DSTATE + n;
    const size_t so0 = (size_t)b * DINNER + d;

    float hin = 0.f;
    for (int c0 = 0; c0 < NCHUNK; c0 += 8) {
        float e[8], dAc[8];
        #pragma unroll
        for (int k = 0; k < 8; ++k) {
            e[k]   = H[ho0 + (size_t)(c0 + k) * hstride];
            dAc[k] = Sdt[so0 + (size_t)(c0 + k) * sstride];
        }
        #pragma unroll
        for (int k = 0; k < 8; ++k) dAc[k] = fast_exp2(Av * dAc[k]);
        #pragma unroll
        for (int k = 0; k < 8; ++k) {
            H[ho0 + (size_t)(c0 + k) * hstride] = hin;
            hin = dAc[k] * hin + e[k];
        }
    }
}

// ---------------------------------------------------------------------------
// phase 3: redo chunk scan from Hin, emit y, fused ymod.
// R22: structured powers-of-w path (verified). Generic fallback kept.
// ---------------------------------------------------------------------------
__global__ __launch_bounds__(256) void scan_phase3(
    const ushort* __restrict__ delta, const ushort* __restrict__ u,
    const ushort* __restrict__ xdbl, const float* __restrict__ negA,
    const float* __restrict__ Hin, const float* __restrict__ Dp,
    const ushort* __restrict__ xr, ushort* __restrict__ yb,
    const int* __restrict__ sflag)
{
    const int idx = blockIdx.x * 256 + threadIdx.x;
    const int d = idx & (DINNER - 1);
    const int b = (idx >> 11) & (BATCH - 1);
    const int c = idx >> 12;
    const int strA = (sflag[1] == 0);

    float h[DSTATE];
    size_t ho = (((size_t)c * BATCH + b) * DINNER + d) * DSTATE;
    #pragma unroll
    for (int n = 0; n < DSTATE; n += 4) {
        floatx4 hv = *(const floatx4*)&Hin[ho + n];
        h[n] = hv[0]; h[n + 1] = hv[1]; h[n + 2] = hv[2]; h[n + 3] = hv[3];
    }

    const float Dpd = Dp[d];
    const int t0 = c * CHUNK;
    size_t bd = ((size_t)b * L_SEQ + t0) * DINNER + d;
    size_t bx = ((size_t)b * L_SEQ + t0) * 96 + DTRANK;
    size_t br = ((size_t)b * L_SEQ + t0) * (2 * DINNER) + DINNER + d;

    if (strA) {
        for (int t = 0; t < CHUNK; ++t) {
            float dt = bf2f(delta[bd]);
            float uv = bf2f(u[bd]);
            float du = dt * uv;
            short8 B0 = *(const short8*)&xdbl[bx];
            short8 B1 = *(const short8*)&xdbl[bx + 8];
            short8 C0 = *(const short8*)&xdbl[bx + 16];
            short8 C1 = *(const short8*)&xdbl[bx + 24];
            float w  = fast_exp2(-dt * LOG2E);        // exp(-dt)
            float w2 = w * w, w4 = w2 * w2, w8 = w4 * w4;
            float p3 = w2 * w, p5 = w4 * w, p6 = w4 * w2, p7 = w4 * p3;
            float dA[16] = {w, w2, p3, w4, p5, p6, p7, w8,
                            w8 * w, w8 * w2, w8 * p3, w8 * w4,
                            w8 * p5, w8 * p6, w8 * p7, w8 * w8};
            float y = 0.f;
            #pragma unroll
            for (int n = 0; n < 8; ++n) {
                h[n] = dA[n] * h[n] + du * bf2f((ushort)B0[n]);
                y += h[n] * bf2f((ushort)C0[n]);
            }
            #pragma unroll
            for (int n = 0; n < 8; ++n) {
                h[8 + n] = dA[8 + n] * h[8 + n] + du * bf2f((ushort)B1[n]);
                y += h[8 + n] * bf2f((ushort)C1[n]);
            }
            float yv = y + uv * Dpd;
            float r  = bf2f(xr[br]);
            yb[bd] = f2bf(yv * silu_f(r));
            bd += DINNER; bx += 96; br += 2 * DINNER;
        }
    } else {
        float Av[DSTATE];
        #pragma unroll
        for (int n = 0; n < DSTATE; ++n)
            Av[n] = negA[d * DSTATE + n];
        for (int t = 0; t < CHUNK; ++t) {
            float dt = bf2f(delta[bd]);
            float uv = bf2f(u[bd]);
            float du = dt * uv;
            short8 B0 = *(const short8*)&xdbl[bx];
            short8 B1 = *(const short8*)&xdbl[bx + 8];
            short8 C0 = *(const short8*)&xdbl[bx + 16];
            short8 C1 = *(const short8*)&xdbl[bx + 24];
            float y = 0.f;
            #pragma unroll
            for (int n = 0; n < 8; ++n) {
                h[n] = fast_exp2(dt * Av[n]) * h[n] + du * bf2f((ushort)B0[n]);
                y += h[n] * bf2f((ushort)C0[n]);
            }
            #pragma unroll
            for (int n = 0; n < 8; ++n) {
                h[8 + n] = fast_exp2(dt * Av[8 + n]) * h[8 + n] + du * bf2f((ushort)B1[n]);
                y += h[8 + n] * bf2f((ushort)C1[n]);
            }
            float yv = y + uv * Dpd;
            float r  = bf2f(xr[br]);
            yb[bd] = f2bf(yv * silu_f(r));
            bd += DINNER; bx += 96; br += 2 * DINNER;
        }
    }
}

// ---------------------------------------------------------------------------
extern "C" void kernel_launch(void* const* d_in, const int* in_sizes, int n_in,
                              void* d_out, int out_size, void* d_ws, size_t ws_size,
                              hipStream_t stream) {
    const void* x_raw      = d_in[0];
    const void* wqkv_raw   = d_in[1];
    const void* bqkv_raw   = d_in[2];
    const void* wao_raw    = d_in[3];
    const void* bao_raw    = d_in[4];
    const void* win_raw    = d_in[5];
    const void* convw_raw  = d_in[6];
    const void* convb_raw  = d_in[7];
    const void* wxp_raw    = d_in[8];
    const void* wdt_raw    = d_in[9];
    const void* bdt_raw    = d_in[10];
    const void* Alog_raw   = d_in[11];
    const void* Dp_raw     = d_in[12];
    const void* wout_raw   = d_in[13];

    const int M = BATCH * L_SEQ;  // 4096

    char* p = (char*)d_ws;
    size_t off = 0;
    auto A_ = [&](size_t bytes) { void* q = p + off; off += (bytes + 255) & ~255ull; return q; };

    ushort* x_b    = (ushort*)A_((size_t)M * NDIM * 2);
    ushort* wqkv_t = (ushort*)A_((size_t)NDIM * 1152 * 2);
    ushort* wao_t  = (ushort*)A_((size_t)NDIM * NDIM * 2);
    ushort* win_t  = (ushort*)A_((size_t)NDIM * 4096 * 2);
    float*  psum   = (float*)x_b;
    ushort* yb     = x_b;
    float*  Sdt    = (float*)(x_b + (size_t)M * DINNER);

    ushort* qkv    = (ushort*)A_((size_t)M * 1152 * 2);
    ushort* att    = (ushort*)A_((size_t)M * NDIM * 2);
    float*  Hend   = (float*)qkv;

    ushort* delta_b = (ushort*)A_((size_t)M * DINNER * 2);

    ushort* wxp_t  = (ushort*)A_((size_t)128 * DINNER * 2);
    ushort* wdt_t  = (ushort*)A_((size_t)DTRANK * DINNER * 2);
    ushort* wout_t = (ushort*)A_((size_t)DINNER * NDIM * 2);
    float*  bqkv_f = (float*)A_(1152 * 4);
    float*  bao_f  = (float*)A_(NDIM * 4);
    float*  convw_f= (float*)A_((size_t)DINNER * DCONV * 4);
    float*  convb_f= (float*)A_(DINNER * 4);
    float*  bdt_f  = (float*)A_(DINNER * 4);
    float*  Alog_f = (float*)A_((size_t)DINNER * DSTATE * 4);
    float*  Dp_f   = (float*)A_(DINNER * 4);
    int*    flag   = (int*)A_(256);
    ushort* x1b    = (ushort*)A_((size_t)M * NDIM * 2);
    ushort* xr     = (ushort*)A_((size_t)M * 4096 * 2);
    ushort* u      = (ushort*)A_((size_t)M * DINNER * 2);
    ushort* xdbl   = (ushort*)A_((size_t)M * 96 * 2);

    ushort* partO = xr;
    float*  partL = (float*)u;

    dim3 blk(256);

    // flag[0] = dtype (written by prep), flag[1] = A-structure mismatch count
    hipMemsetAsync(flag, 0, 8, stream);

    // 0. one-launch prep (probe + x cvt + 6 transposes + pad + small params)
    prep_kernel<<<dim3(25473), blk, 0, stream>>>(
        x_raw, wqkv_raw, wao_raw, win_raw, wxp_raw, wdt_raw, wout_raw,
        bqkv_raw, bao_raw, convw_raw, convb_raw, bdt_raw, Alog_raw, Dp_raw,
        x_b, wqkv_t, wao_t, win_t, wxp_t, wdt_t, wout_t,
        bqkv_f, bao_f, convw_f, convb_f, bdt_f, Alog_f, Dp_f, flag);

    // 1. qkv = x @ wqkv + bqkv   (swap=0)
    gemm128<<<dim3(1152 / 128, M / 128), blk, 0, stream>>>(
        x_b, NDIM, wqkv_t, bqkv_f, nullptr, qkv, nullptr, nullptr, 1152, NDIM, 0, NDIM, nullptr, 0);

    // 2. flash attention (dense LPT 1D grid: 160 work entries x 8 hgb) + combine
    flash_attn_split<<<dim3(1280), blk, 0, stream>>>(
        qkv, att, partO, partL);
    attn_combine<<<dim3(1536), blk, 0, stream>>>(partO, partL, att);

    // 3. x1 = att @ w_ao + b_ao + x   (swap=0)
    gemm128<<<dim3(NDIM / 128, M / 128), blk, 0, stream>>>(
        att, NDIM, wao_t, bao_f, x_b, x1b, nullptr, nullptr, NDIM, NDIM, 0, NDIM, nullptr, 0);

    // 4. xr = x1 @ w_in   (swap=1: XCD-local A-strip)
    gemm128<<<dim3(M / 128, 4096 / 128), blk, 0, stream>>>(
        x1b, NDIM, win_t, nullptr, nullptr, xr, nullptr, nullptr, 4096, NDIM, 0, NDIM, nullptr, 1);

    // 5. conv + silu -> u  (1 channel/thread, 16 L/thread)
    conv_silu<<<dim3((M / 16) * (DINNER / 256)), blk, 0, stream>>>(xr, convw_f, convb_f, u);

    // 6. xdbl = u @ w_xproj  (split-K=8 over padded N=128)
    gemm128<<<dim3(1, M / 128, 8), blk, 0, stream>>>(
        u, DINNER, wxp_t, nullptr, nullptr, nullptr, nullptr, nullptr, 128, DINNER, 0, DINNER / 8, psum, 0);
    combine_xdbl<<<dim3(M * 96 / 256), blk, 0, stream>>>(psum, xdbl);

    // 7. delta = softplus(xdbl[:, :64] @ w_dt + b_dt)  (swap=0)
    gemm128<<<dim3(DINNER / 128, M / 128), blk, 0, stream>>>(
        xdbl, 96, wdt_t, bdt_f, nullptr, delta_b, nullptr, nullptr, DINNER, DTRANK, 1, DTRANK, nullptr, 0);

    // 8. chunked selective scan (+fused ymod) -> yb
    scan_phase1<<<dim3(NCHUNK * BATCH * DINNER * 2 / 256), blk, 0, stream>>>(
        delta_b, u, xdbl, Alog_f, Hend, Sdt, flag);
    scan_phase2<<<dim3(BATCH * DINNER * DSTATE / 256), blk, 0, stream>>>(
        Hend, Sdt, Alog_f);
    scan_phase3<<<dim3(NCHUNK * BATCH * DINNER / 256), blk, 0, stream>>>(
        delta_b, u, xdbl, Alog_f, Hend, Dp_f, xr, yb, flag);

    // 10. out = yb @ w_out + x1  (swap=1)
    gemm128<<<dim3(M / 128, NDIM / 128), blk, 0, stream>>>(
        yb, DINNER, wout_t, nullptr, x1b, (ushort*)d_out, (float*)d_out, flag, NDIM, DINNER, 0, DINNER, nullptr, 1);
}

// Round 12
// 398.716 us; speedup vs baseline: 1.0392x; 1.0392x over previous
//
#include <hip/hip_runtime.h>

#define L_SEQ   2048
#define BATCH   2
#define NDIM    1024
#define NHEADS  16
#define HD      64
#define DSTATE  16
#define DCONV   4
#define DINNER  2048
#define DTRANK  64
#define CHUNK   32
#define NCHUNK  (L_SEQ / CHUNK)   // 64
#define SPLIT_KT 8                // KV tiles per attention split
#define LOG2E   1.4426950408889634f

typedef short  short8  __attribute__((ext_vector_type(8)));
typedef float  floatx4 __attribute__((ext_vector_type(4)));

#define AS1 __attribute__((address_space(1)))
#define AS3 __attribute__((address_space(3)))

__device__ __forceinline__ float bf2f(ushort u) {
    union { uint i; float f; } v; v.i = ((uint)u) << 16; return v.f;
}
// bf16 convert: native v_cvt_pk_bf16_f32 (RNE, 1 VALU op) when available;
// manual RNE fallback (4 ops). [R13: manual f2bf was ~40% of flash VALU]
#if defined(__has_builtin) && __has_builtin(__builtin_amdgcn_cvt_pk_bf16_f32)
__device__ __forceinline__ ushort f2bf(float f) {
    auto p = __builtin_amdgcn_cvt_pk_bf16_f32(f, f);
    union { decltype(p) v; ushort u[2]; } cv; cv.v = p;
    return cv.u[0];
}
__device__ __forceinline__ uint pk2bf(float lo, float hi) {
    auto p = __builtin_amdgcn_cvt_pk_bf16_f32(lo, hi);
    union { decltype(p) v; uint u; } cv; cv.v = p;
    return cv.u;
}
#else
__device__ __forceinline__ ushort f2bf(float f) {
    uint x = __float_as_uint(f);
    uint r = (x + 0x7fffu + ((x >> 16) & 1u)) >> 16;
    return (ushort)r;
}
__device__ __forceinline__ uint pk2bf(float lo, float hi) {
    return ((uint)f2bf(hi) << 16) | (uint)f2bf(lo);
}
#endif
// raw v_exp_f32 (2^x); log2(e) pre-folded into operands.
#if defined(__has_builtin) && __has_builtin(__builtin_amdgcn_exp2f)
__device__ __forceinline__ float fast_exp2(float x) {
    return __builtin_amdgcn_exp2f(x);
}
#else
__device__ __forceinline__ float fast_exp2(float x) {
    return __expf(x * 0.6931471805599453f);
}
#endif
__device__ __forceinline__ float silu_f(float x) {
    return x / (1.f + __expf(-x));
}
__device__ __forceinline__ void gld_lds16(const void* g, void* l) {
    __builtin_amdgcn_global_load_lds((const AS1 uint*)g, (AS3 uint*)l, 16, 0, 0);
}
__device__ __forceinline__ float cvt_one(const void* s, int i, int f) {
    return f ? ((const float*)s)[i] : bf2f(((const ushort*)s)[i]);
}

// ---------------------------------------------------------------------------
// MEGA PREP: one launch: dtype-probe (per-block), x convert, 6 weight
// transposes, wxp pad, small-param f32 conversion.
// R21: Alog_f stores negA2 = -exp(A_log)*log2(e).
// R22: verifies A-structure into flag[1] (powers-of-w gate). Verified.
// R24: x convert vectorized x8 — bf16 path is a pure short8 copy
// (f2bf(bf2f(u)) == u exactly); f32 path reads 2x float4. 16384->2048
// blocks; all segment offsets shifted accordingly (grid 25473->11137).
// ---------------------------------------------------------------------------
__global__ __launch_bounds__(256) void prep_kernel(
    const void* __restrict__ x_raw,
    const void* __restrict__ wqkv, const void* __restrict__ wao,
    const void* __restrict__ win,  const void* __restrict__ wxp,
    const void* __restrict__ wdt,  const void* __restrict__ wout,
    const void* __restrict__ bqkv, const void* __restrict__ bao,
    const void* __restrict__ convw, const void* __restrict__ convb,
    const void* __restrict__ bdt,  const void* __restrict__ Alog,
    const void* __restrict__ Dp,
    ushort* __restrict__ x_b, ushort* __restrict__ wqkv_t,
    ushort* __restrict__ wao_t, ushort* __restrict__ win_t,
    ushort* __restrict__ wxp_t, ushort* __restrict__ wdt_t,
    ushort* __restrict__ wout_t,
    float* __restrict__ bqkv_f, float* __restrict__ bao_f,
    float* __restrict__ convw_f, float* __restrict__ convb_f,
    float* __restrict__ bdt_f, float* __restrict__ Alog_f,
    float* __restrict__ Dp_f, int* __restrict__ flag)
{
    __shared__ int cnt;
    __shared__ float tile[32][33];
    if (threadIdx.x == 0) cnt = 0;
    __syncthreads();
    {
        ushort w = ((const ushort*)x_raw)[threadIdx.x];
        int e = (w >> 7) & 0xff;
        if (w != 0 && (e < 100 || e > 140)) atomicAdd(&cnt, 1);
    }
    __syncthreads();
    const int f = (cnt >= 16) ? 1 : 0;
    if (blockIdx.x == 0 && threadIdx.x == 0) *flag = f;

    int id = blockIdx.x;
    if (id < 2048) {                                // x convert, 8/thread
        int i = (id * 256 + threadIdx.x) * 8;
        if (f) {
            floatx4 a = *(const floatx4*)((const float*)x_raw + i);
            floatx4 c = *(const floatx4*)((const float*)x_raw + i + 4);
            short8 o;
            o[0] = (short)f2bf(a[0]); o[1] = (short)f2bf(a[1]);
            o[2] = (short)f2bf(a[2]); o[3] = (short)f2bf(a[3]);
            o[4] = (short)f2bf(c[0]); o[5] = (short)f2bf(c[1]);
            o[6] = (short)f2bf(c[2]); o[7] = (short)f2bf(c[3]);
            *(short8*)&x_b[i] = o;
        } else {
            *(short8*)&x_b[i] = *(const short8*)((const ushort*)x_raw + i);
        }
        return;
    }
    id -= 2048;

    const void* src = nullptr; ushort* dst = nullptr; int K = 0, N = 0;
    if (id < 1152)                     { src = wqkv; dst = wqkv_t; K = 1024; N = 1152; }
    else if ((id -= 1152) < 1024)      { src = wao;  dst = wao_t;  K = 1024; N = 1024; }
    else if ((id -= 1024) < 4096)      { src = win;  dst = win_t;  K = 1024; N = 4096; }
    else if ((id -= 4096) < 192)       { src = wxp;  dst = wxp_t;  K = 2048; N = 96;   }
    else if ((id -= 192)  < 128)       { src = wdt;  dst = wdt_t;  K = 64;   N = 2048; }
    else if ((id -= 128)  < 2048)      { src = wout; dst = wout_t; K = 2048; N = 1024; }
    else {
        id -= 2048;
        if (id < 256) {                              // wxp pad rows 96..127
            wxp_t[(size_t)96 * DINNER + id * 256 + threadIdx.x] = 0;
        } else {                                     // small params
            int i = (id - 256) * 256 + threadIdx.x;
            if      (i < 1152)   bqkv_f[i]          = cvt_one(bqkv,  i,          f);
            else if (i < 2176)   bao_f[i - 1152]    = cvt_one(bao,   i - 1152,   f);
            else if (i < 10368)  convw_f[i - 2176]  = cvt_one(convw, i - 2176,   f);
            else if (i < 12416)  convb_f[i - 10368] = cvt_one(convb, i - 10368,  f);
            else if (i < 14464)  bdt_f[i - 12416]   = cvt_one(bdt,   i - 12416,  f);
            else if (i < 47232) {
                int ai = i - 14464;
                float v = -__expf(cvt_one(Alog, ai, f)) * LOG2E;   // negA2
                Alog_f[ai] = v;
                int np1 = (ai & 15) + 1;
                float expv = -(float)np1 * LOG2E;
                if (fabsf(v - expv) > 1e-5f * (float)np1)
                    atomicAdd(flag + 1, 1);
            }
            else if (i < 49280)  Dp_f[i - 47232]    = cvt_one(Dp,    i - 47232,  f);
        }
        return;
    }

    const int ntn = N / 32;
    const int n0 = (id % ntn) * 32, k0 = (id / ntn) * 32;
    const int tx = threadIdx.x & 31, ty = threadIdx.x >> 5;
    #pragma unroll
    for (int r = 0; r < 4; ++r) {
        size_t o = (size_t)(k0 + ty + r * 8) * N + n0 + tx;
        tile[ty + r * 8][tx] = cvt_one(src, (int)o, f);
    }
    __syncthreads();
    #pragma unroll
    for (int r = 0; r < 4; ++r) {
        int n = n0 + ty + r * 8;
        dst[(size_t)n * K + k0 + tx] = f2bf(tile[tx][ty + r * 8]);
    }
}

// ---------------------------------------------------------------------------
// MFMA GEMM: 128x128 tile, BK=64, XOR k-slot swizzle.
// R17: bijective XCD swizzle (T1) + LDS-staged f32 epilogue.
// R19: T3-minimum 2-phase double-buffered staging.
// ---------------------------------------------------------------------------
__global__ __launch_bounds__(256) void gemm128(
    const ushort* __restrict__ A, int lda,
    const ushort* __restrict__ Wt,
    const float* __restrict__ bias,
    const ushort* __restrict__ resb,
    ushort* __restrict__ outb, float* __restrict__ outf,
    const int* __restrict__ dtflag,
    int N, int K, int act, int klen, float* __restrict__ psum, int swap)
{
    __shared__ __align__(16) char smem[65536];   // 2 x (As 16K + Bs 16K)

    const int tid  = threadIdx.x;
    const int wave = tid >> 6;
    const int lane = tid & 63;
    const int wm = (wave >> 1) * 64;
    const int wn = (wave & 1) * 64;
    const int fm = lane & 15;
    const int quad = lane >> 4;

    // T1 bijective XCD swizzle (nwg % 8 == 0 at every call site)
    int bx = blockIdx.x, by = blockIdx.y;
    {
        const int gx = gridDim.x;
        const int nwg = gx * gridDim.y;
        const int id = by * gx + bx;
        const int qq = nwg >> 3;
        const int sid = (id & 7) * qq + (id >> 3);
        bx = sid % gx; by = sid / gx;
    }
    const int m0 = (swap ? bx : by) * 128;
    const int n0 = (swap ? by : bx) * 128;

    floatx4 acc[4][4];
    #pragma unroll
    for (int i = 0; i < 4; ++i)
        #pragma unroll
        for (int j = 0; j < 4; ++j) acc[i][j] = (floatx4){0.f, 0.f, 0.f, 0.f};

    int rowv[4], kgv[4];
    #pragma unroll
    for (int j = 0; j < 4; ++j) {
        int c = wave * 256 + j * 64 + lane;
        rowv[j] = c >> 3;
        kgv[j]  = (((c & 7) ^ ((c >> 3) & 7))) * 8;
    }

    const int kbeg = psum ? (blockIdx.z * klen) : 0;
    const int kend = kbeg + klen;

    auto stage = [&](int buf, int k0) {
        ushort* As = (ushort*)(smem + buf * 32768);
        ushort* Bs = (ushort*)(smem + buf * 32768 + 16384);
        #pragma unroll
        for (int j = 0; j < 4; ++j)
            gld_lds16(A  + (size_t)(m0 + rowv[j]) * lda + k0 + kgv[j],
                      &As[(wave * 256 + j * 64) * 8]);
        #pragma unroll
        for (int j = 0; j < 4; ++j)
            gld_lds16(Wt + (size_t)(n0 + rowv[j]) * K   + k0 + kgv[j],
                      &Bs[(wave * 256 + j * 64) * 8]);
    };

    // prologue: fill buffer 0, drain, sync
    stage(0, kbeg);
    __syncthreads();

    int cur = 0;
    for (int k0 = kbeg; k0 < kend; k0 += 64) {
        if (k0 + 64 < kend) stage(cur ^ 1, k0 + 64);   // overlap with compute
        const ushort* As = (const ushort*)(smem + cur * 32768);
        const ushort* Bs = (const ushort*)(smem + cur * 32768 + 16384);

        #pragma unroll
        for (int h = 0; h < 2; ++h) {
            short8 af[4], bf[4];
            #pragma unroll
            for (int i = 0; i < 4; ++i) {
                int row = wm + i * 16 + fm;
                int slot = (h * 4 + quad) ^ (row & 7);
                af[i] = *(const short8*)&As[row * 64 + slot * 8];
            }
            #pragma unroll
            for (int j = 0; j < 4; ++j) {
                int row = wn + j * 16 + fm;
                int slot = (h * 4 + quad) ^ (row & 7);
                bf[j] = *(const short8*)&Bs[row * 64 + slot * 8];
            }
            #pragma unroll
            for (int i = 0; i < 4; ++i)
                #pragma unroll
                for (int j = 0; j < 4; ++j)
                    acc[i][j] = __builtin_amdgcn_mfma_f32_16x16x32_bf16(af[i], bf[j], acc[i][j], 0, 0, 0);
        }
        __syncthreads();   // drains next-tile stage + syncs buffer handoff
        cur ^= 1;
    }

    if (psum) {
        int mgrid = swap ? gridDim.x : gridDim.y;
        float* po = psum + (size_t)blockIdx.z * ((size_t)mgrid * 128) * N;
        #pragma unroll
        for (int j = 0; j < 4; ++j) {
            int col = n0 + wn + j * 16 + fm;
            #pragma unroll
            for (int i = 0; i < 4; ++i) {
                int rowb = m0 + wm + i * 16 + quad * 4;
                #pragma unroll
                for (int r = 0; r < 4; ++r)
                    po[(size_t)(rowb + r) * N + col] = acc[i][j][r];
            }
        }
        return;
    }

    // ---- R17 staged epilogue: f32 through LDS, coalesced stores ----
    const int flagv = dtflag ? *dtflag : 0;
    const bool wf = dtflag ? (flagv != 0) : (outf != nullptr);
    float* Cs = (float*)smem;               // [64][132] f32 = 33792 B (aliases bufs)
    const int lrw = (wm >> 1) + quad * 4;   // + ih*16 + r
    #pragma unroll
    for (int p = 0; p < 2; ++p) {
        #pragma unroll
        for (int ih = 0; ih < 2; ++ih) {
            const int i = 2 * p + ih;
            #pragma unroll
            for (int j = 0; j < 4; ++j) {
                float bvv = bias ? bias[n0 + wn + j * 16 + fm] : 0.f;
                #pragma unroll
                for (int r = 0; r < 4; ++r) {
                    float v = acc[i][j][r] + bvv;
                    if (act == 1)
                        v = fmaxf(v, 0.f) + __logf(1.f + __expf(-fabsf(v)));
                    Cs[(lrw + ih * 16 + r) * 132 + wn + j * 16 + fm] = v;
                }
            }
        }
        __syncthreads();
        #pragma unroll
        for (int g = 0; g < 4; ++g) {
            const int lr   = g * 16 + (tid >> 4);
            const int colc = (tid & 15) * 8;
            const int grow = m0 + (lr >> 5) * 64 + (2 * p + ((lr >> 4) & 1)) * 16 + (lr & 15);
            const size_t o = (size_t)grow * N + n0 + colc;
            floatx4 v0 = *(const floatx4*)&Cs[lr * 132 + colc];
            floatx4 v1 = *(const floatx4*)&Cs[lr * 132 + colc + 4];
            float vv[8] = {v0[0], v0[1], v0[2], v0[3], v1[0], v1[1], v1[2], v1[3]};
            if (resb) {
                short8 rs = *(const short8*)&resb[o];
                #pragma unroll
                for (int k = 0; k < 8; ++k) vv[k] += bf2f((ushort)rs[k]);
            }
            if (wf) {
                *(floatx4*)&outf[o]     = (floatx4){vv[0], vv[1], vv[2], vv[3]};
                *(floatx4*)&outf[o + 4] = (floatx4){vv[4], vv[5], vv[6], vv[7]};
            } else {
                short8 ov;
                #pragma unroll
                for (int k = 0; k < 8; ++k) ov[k] = (short)f2bf(vv[k]);
                *(short8*)&outb[o] = ov;
            }
        }
        __syncthreads();
    }
}

// ---------------------------------------------------------------------------
// combine split-K partials (4096 x 128 padded) -> xdbl bf16 (stride 96).
// ---------------------------------------------------------------------------
__global__ __launch_bounds__(256) void combine_xdbl(
    const float* __restrict__ psum, ushort* __restrict__ xdbl)
{
    int idx = blockIdx.x * 256 + threadIdx.x;
    int row = idx / 96, col = idx - row * 96;
    float s = 0.f;
    #pragma unroll
    for (int z = 0; z < 8; ++z)
        s += psum[(size_t)z * 4096 * 128 + row * 128 + col];
    xdbl[idx] = f2bf(s);
}

// ---------------------------------------------------------------------------
// Flash MQA attention, split-KV, static-max softmax.
// R16: swapped QK^T (T12) + in-register bpermute P exchange, LDS 18KB.
// R18: dense LPT 1D grid. R21: exp via v_exp with folded scale.
// R24: REVERTED to exact R22 structure (R23's V-linear + 64 scalar
// ds_read_u16/thread gather regressed 47->60us; read-op accounting error).
// ---------------------------------------------------------------------------
__global__ __launch_bounds__(256) void flash_attn_split(
    const ushort* __restrict__ qkv, ushort* __restrict__ att,
    ushort* __restrict__ partO, float* __restrict__ partL)
{
    __shared__ __align__(16) ushort Ks[64 * 72];
    __shared__ __align__(16) ushort Vt[64 * 72];

    // ---- R18 dense LPT decode ----
    const int id  = blockIdx.x;
    const int e   = id >> 3;
    const int hgb = id & 7;
    const int hg  = hgb >> 1;
    const int b   = hgb & 1;
    int tile, s;
    if (e < 104) {
        if      (e < 50)  { s = 0; tile = 63 - e; }
        else if (e < 84)  { s = 1; tile = 63 - (e - 50); }
        else if (e < 102) { s = 2; tile = 63 - (e - 84); }
        else              { s = 3; tile = 63 - (e - 102); }
    } else {
        const int rem = e - 104;
        const int w   = 7 - (rem >> 3);
        s    = (rem & 7) >> 1;
        tile = 2 * (8 * s + w) - 2 + (rem & 1);
    }

    const int q0 = tile * 32;
    const int nkv = (q0 >> 6) + 1;
    const int nsplit = (nkv + SPLIT_KT - 1) / SPLIT_KT;
    const int kt0 = s * SPLIT_KT;
    const int kt1 = (nkv < kt0 + SPLIT_KT) ? nkv : (kt0 + SPLIT_KT);

    const int tid  = threadIdx.x;
    const int wave = tid >> 6;
    const int lane = tid & 63;
    const int fm   = lane & 15;
    const int quad = lane >> 4;
    const int h    = hg * 4 + wave;

    const int srow = tid >> 3;
    const int scol = (tid & 7) * 8;
    const int vsw  = (tid & 7) << 3;

    // bpermute byte-addresses for the P^T -> A-fragment exchange
    const int addrA = (fm + (quad & 1) * 32) * 4;
    const int addrB = addrA + 64;
    const bool jlo_sel = (quad < 2);

    short8 qf[2][2];
    #pragma unroll
    for (int i = 0; i < 2; ++i)
        #pragma unroll
        for (int kh = 0; kh < 2; ++kh)
            qf[i][kh] = *(const short8*)(qkv +
                (size_t)(b * L_SEQ + q0 + i * 16 + fm) * 1152 + h * HD + kh * 32 + quad * 8);

    floatx4 acc[2][4];
    float l_lane[2];
    #pragma unroll
    for (int i = 0; i < 2; ++i) {
        #pragma unroll
        for (int j = 0; j < 4; ++j) acc[i][j] = (floatx4){0.f, 0.f, 0.f, 0.f};
        l_lane[i] = 0.f;
    }

    // --- prefetch first tile's K/V into registers -------------------------
    short8 kreg[2], vreg[2];
    {
        const int kv0 = kt0 * 64;
        #pragma unroll
        for (int pass = 0; pass < 2; ++pass) {
            int row = srow + pass * 32;
            const ushort* kp = qkv + (size_t)(b * L_SEQ + kv0 + row) * 1152 + NDIM + scol;
            kreg[pass] = *(const short8*)kp;
            vreg[pass] = *(const short8*)(kp + HD);
        }
    }

    for (int kt = kt0; kt < kt1; ++kt) {
        const int kv0 = kt * 64;
        __syncthreads();
        // stage from registers (vmcnt wait lands here, hidden under prev compute)
        #pragma unroll
        for (int pass = 0; pass < 2; ++pass) {
            int row = srow + pass * 32;
            *(short8*)&Ks[row * 72 + scol] = kreg[pass];
            int mw = row ^ vsw;
            #pragma unroll
            for (int i2 = 0; i2 < 8; ++i2) Vt[(scol + i2) * 72 + mw] = (ushort)vreg[pass][i2];
        }
        __syncthreads();

        // issue next tile's loads now; first use is next iteration's stage
        if (kt + 1 < kt1) {
            const int kv0n = (kt + 1) * 64;
            #pragma unroll
            for (int pass = 0; pass < 2; ++pass) {
                int row = srow + pass * 32;
                const ushort* kp = qkv + (size_t)(b * L_SEQ + kv0n + row) * 1152 + NDIM + scol;
                kreg[pass] = *(const short8*)kp;
                vreg[pass] = *(const short8*)(kp + HD);
            }
        }

        // QK^T swapped: spT[j][i] = S^T, lane holds (kv=j*16+quad*4+r, q=i*16+fm)
        floatx4 spT[4][2];
        __builtin_amdgcn_s_setprio(1);
        #pragma unroll
        for (int j = 0; j < 4; ++j) {
            short8 kf0 = *(const short8*)&Ks[(j * 16 + fm) * 72 + quad * 8];
            short8 kf1 = *(const short8*)&Ks[(j * 16 + fm) * 72 + 32 + quad * 8];
            #pragma unroll
            for (int i = 0; i < 2; ++i) {
                floatx4 z = (floatx4){0.f, 0.f, 0.f, 0.f};
                z = __builtin_amdgcn_mfma_f32_16x16x32_bf16(kf0, qf[i][0], z, 0, 0, 0);
                z = __builtin_amdgcn_mfma_f32_16x16x32_bf16(kf1, qf[i][1], z, 0, 0, 0);
                spT[j][i] = z;
            }
        }
        __builtin_amdgcn_s_setprio(0);

        const bool diag = (kt == nkv - 1);
        #pragma unroll
        for (int j = 0; j < 4; ++j)
            #pragma unroll
            for (int i = 0; i < 2; ++i) {
                #pragma unroll
                for (int r = 0; r < 4; ++r) {
                    float p = fast_exp2(spT[j][i][r] * 0.18033688011112042f);  // 0.125*log2e
                    if (diag) {
                        int kvg = kv0 + j * 16 + quad * 4 + r;
                        int qg  = q0 + i * 16 + fm;
                        if (kvg > qg) p = 0.f;
                    }
                    spT[j][i][r] = p;
                    l_lane[i] += p;
                }
            }

        // pack to bf16 dwords: w0 = kv pair (r0,r1), w1 = (r2,r3)
        uint w0[4][2], w1[4][2];
        #pragma unroll
        for (int j = 0; j < 4; ++j)
            #pragma unroll
            for (int i = 0; i < 2; ++i) {
                w0[j][i] = pk2bf(spT[j][i][0], spT[j][i][1]);
                w1[j][i] = pk2bf(spT[j][i][2], spT[j][i][3]);
            }

        // in-register P^T -> PV A-fragment via ds_bpermute (no LDS buffer)
        short8 pf[2][2];
        #pragma unroll
        for (int i = 0; i < 2; ++i)
            #pragma unroll
            for (int kh = 0; kh < 2; ++kh) {
                const int jl = kh * 2, jh = kh * 2 + 1;
                uint a0 = (uint)__builtin_amdgcn_ds_bpermute(addrA, (int)w0[jl][i]);
                uint a1 = (uint)__builtin_amdgcn_ds_bpermute(addrA, (int)w0[jh][i]);
                uint b0 = (uint)__builtin_amdgcn_ds_bpermute(addrA, (int)w1[jl][i]);
                uint b1 = (uint)__builtin_amdgcn_ds_bpermute(addrA, (int)w1[jh][i]);
                uint c0 = (uint)__builtin_amdgcn_ds_bpermute(addrB, (int)w0[jl][i]);
                uint c1 = (uint)__builtin_amdgcn_ds_bpermute(addrB, (int)w0[jh][i]);
                uint d0 = (uint)__builtin_amdgcn_ds_bpermute(addrB, (int)w1[jl][i]);
                uint d1 = (uint)__builtin_amdgcn_ds_bpermute(addrB, (int)w1[jh][i]);
                union { uint u[4]; short8 s; } cv;
                cv.u[0] = jlo_sel ? a0 : a1;
                cv.u[1] = jlo_sel ? b0 : b1;
                cv.u[2] = jlo_sel ? c0 : c1;
                cv.u[3] = jlo_sel ? d0 : d1;
                pf[i][kh] = cv.s;
            }

        __builtin_amdgcn_s_setprio(1);
        #pragma unroll
        for (int dj = 0; dj < 4; ++dj) {
            int d = dj * 16 + fm;
            int sw8 = ((d >> 3) & 7) << 3;
            short8 vf0 = *(const short8*)&Vt[d * 72 + ((quad * 8) ^ sw8)];
            short8 vf1 = *(const short8*)&Vt[d * 72 + ((32 + quad * 8) ^ sw8)];
            #pragma unroll
            for (int i = 0; i < 2; ++i) {
                acc[i][dj] = __builtin_amdgcn_mfma_f32_16x16x32_bf16(pf[i][0], vf0, acc[i][dj], 0, 0, 0);
                acc[i][dj] = __builtin_amdgcn_mfma_f32_16x16x32_bf16(pf[i][1], vf1, acc[i][dj], 0, 0, 0);
            }
        }
        __builtin_amdgcn_s_setprio(0);
    }

    // reduce l across the 4 quads (kv partial sums); all lanes then hold
    // the full row-sum for q = i*16+fm
    #pragma unroll
    for (int i = 0; i < 2; ++i) {
        float rs = l_lane[i];
        rs += __shfl_xor(rs, 16);
        rs += __shfl_xor(rs, 32);
        l_lane[i] = rs;
    }

    if (nsplit == 1) {
        #pragma unroll
        for (int i = 0; i < 2; ++i) {
            float inv[4];
            #pragma unroll
            for (int r = 0; r < 4; ++r)
                inv[r] = 1.f / __shfl(l_lane[i], quad * 4 + r, 16);
            #pragma unroll
            for (int dj = 0; dj < 4; ++dj)
                #pragma unroll
                for (int r = 0; r < 4; ++r) {
                    int q = q0 + i * 16 + quad * 4 + r;
                    att[(size_t)(b * L_SEQ + q) * NDIM + h * HD + dj * 16 + fm] =
                        f2bf(acc[i][dj][r] * inv[r]);
                }
        }
    } else {
        size_t pbase = ((size_t)((s * 2 + b) * 16 + h)) * L_SEQ;
        #pragma unroll
        for (int i = 0; i < 2; ++i)
            #pragma unroll
            for (int dj = 0; dj < 4; ++dj)
                #pragma unroll
                for (int r = 0; r < 4; ++r) {
                    int q = q0 + i * 16 + quad * 4 + r;
                    partO[(pbase + q) * 64 + dj * 16 + fm] = f2bf(acc[i][dj][r]);
                }
        if (lane < 16) {
            #pragma unroll
            for (int i = 0; i < 2; ++i)
                partL[pbase + q0 + i * 16 + fm] = l_lane[i];
        }
    }
}

// ---------------------------------------------------------------------------
// combine attention split partials for q >= 512.
// ---------------------------------------------------------------------------
__global__ __launch_bounds__(256) void attn_combine(
    const ushort* __restrict__ partO, const float* __restrict__ partL,
    ushort* __restrict__ att)
{
    int gid = blockIdx.x * 256 + threadIdx.x;
    int t8 = gid & 7;
    int row = gid >> 3;
    int q  = 512 + (row % 1536);
    int bh = row / 1536;
    int b = bh >> 4, h = bh & 15;
    int nsplit = (((q >> 5) >> 1) + 1 + SPLIT_KT - 1) / SPLIT_KT;

    float sum[8] = {0.f, 0.f, 0.f, 0.f, 0.f, 0.f, 0.f, 0.f};
    float L = 0.f;
    for (int s = 0; s < nsplit; ++s) {
        size_t pbase = ((size_t)((s * 2 + b) * 16 + h)) * L_SEQ + q;
        L += partL[pbase];
        short8 o = *(const short8*)&partO[pbase * 64 + t8 * 8];
        #pragma unroll
        for (int k = 0; k < 8; ++k) sum[k] += bf2f((ushort)o[k]);
    }
    float inv = 1.f / L;
    short8 outv;
    #pragma unroll
    for (int k = 0; k < 8; ++k) outv[k] = (short)f2bf(sum[k] * inv);
    *(short8*)&att[((size_t)(b * L_SEQ + q)) * NDIM + h * HD + t8 * 8] = outv;
}

// ---------------------------------------------------------------------------
// depthwise conv (window 4, left pad 3) + bias + silu.
// R15: 1 channel/thread, 16 L-positions/thread — coalesced weights+acts.
// ---------------------------------------------------------------------------
__global__ __launch_bounds__(256) void conv_silu(
    const ushort* __restrict__ xr, const float* __restrict__ conv_w,
    const float* __restrict__ conv_b, ushort* __restrict__ u)
{
    const int c   = ((blockIdx.x & 7) << 8) + threadIdx.x;  // 0..2047
    const int bl0 = (blockIdx.x >> 3) << 4;                 // 0..4080 step 16
    const int l0  = bl0 & (L_SEQ - 1);                      // pos within batch

    const floatx4 wv = *(const floatx4*)&conv_w[c * DCONV];
    const float bias = conv_b[c];

    float xv[19];
    #pragma unroll
    for (int t = 0; t < 19; ++t) {
        int ls = l0 - 3 + t;
        xv[t] = (ls >= 0)
              ? bf2f(xr[(size_t)(bl0 - 3 + t) * (2 * DINNER) + c])
              : 0.f;
    }

    #pragma unroll
    for (int t = 0; t < 16; ++t) {
        float a = bias + xv[t] * wv[0] + xv[t + 1] * wv[1]
                       + xv[t + 2] * wv[2] + xv[t + 3] * wv[3];
        u[(size_t)(bl0 + t) * DINNER + c] = f2bf(silu_f(a));
    }
}

// ---------------------------------------------------------------------------
// Chunked selective scan, phase 1.  negA2 = -exp(A_log)*log2e (prep).
// R20 half-split kept. R22: structured powers-of-w path (verified).
// ---------------------------------------------------------------------------
__global__ __launch_bounds__(256) void scan_phase1(
    const ushort* __restrict__ delta, const ushort* __restrict__ u,
    const ushort* __restrict__ xdbl, const float* __restrict__ negA,
    float* __restrict__ Hend, float* __restrict__ Sdt,
    const int* __restrict__ sflag)
{
    const int idx  = blockIdx.x * 256 + threadIdx.x;
    const int lane = idx & 63;
    const int g    = idx >> 6;
    const int half = lane >> 5;                       // 0: n 0-7, 1: n 8-15
    const int d    = ((g & 63) << 5) + (lane & 31);
    const int b    = (g >> 6) & (BATCH - 1);
    const int c    = g >> 7;
    const int strA = (sflag[1] == 0);

    float h[8];
    #pragma unroll
    for (int n = 0; n < 8; ++n) h[n] = 0.f;

    const int t0 = c * CHUNK;
    size_t bd = ((size_t)b * L_SEQ + t0) * DINNER + d;
    size_t bx = ((size_t)b * L_SEQ + t0) * 96 + DTRANK + half * 8;
    float sdt = 0.f;

    if (strA) {
        for (int t = 0; t < CHUNK; ++t) {
            float dt = bf2f(delta[bd]);
            float uv = bf2f(u[bd]);
            sdt += dt;
            float du = dt * uv;
            short8 B0 = *(const short8*)&xdbl[bx];
            float w  = fast_exp2(-dt * LOG2E);        // exp(-dt)
            float w2 = w * w, w4 = w2 * w2, w8 = w4 * w4;
            float p3 = w2 * w;
            float q[8] = {w, w2, p3, w4, w4 * w, w4 * w2, w4 * p3, w8};
            float sc = half ? w8 : 1.f;
            #pragma unroll
            for (int n = 0; n < 8; ++n)
                h[n] = (q[n] * sc) * h[n] + du * bf2f((ushort)B0[n]);
            bd += DINNER; bx += 96;
        }
    } else {
        float Av[8];
        #pragma unroll
        for (int n = 0; n < 8; ++n)
            Av[n] = negA[d * DSTATE + half * 8 + n];
        for (int t = 0; t < CHUNK; ++t) {
            float dt = bf2f(delta[bd]);
            float uv = bf2f(u[bd]);
            sdt += dt;
            float du = dt * uv;
            short8 B0 = *(const short8*)&xdbl[bx];
            #pragma unroll
            for (int n = 0; n < 8; ++n)
                h[n] = fast_exp2(dt * Av[n]) * h[n] + du * bf2f((ushort)B0[n]);
            bd += DINNER; bx += 96;
        }
    }

    size_t ho = (((size_t)c * BATCH + b) * DINNER + d) * DSTATE + half * 8;
    *(floatx4*)&Hend[ho]     = (floatx4){h[0], h[1], h[2], h[3]};
    *(floatx4*)&Hend[ho + 4] = (floatx4){h[4], h[5], h[6], h[7]};
    if (half == 0)
        Sdt[((size_t)c * BATCH + b) * DINNER + d] = sdt;
}

// ---------------------------------------------------------------------------
// phase 2: in-place exclusive combine over 64 chunks.
// R19: batched 8-wide load/exp prefetch.
// ---------------------------------------------------------------------------
__global__ __launch_bounds__(256) void scan_phase2(
    float* __restrict__ H, const float* __restrict__ Sdt,
    const float* __restrict__ negA)
{
    const int idx = blockIdx.x * 256 + threadIdx.x;
    const int n = idx & (DSTATE - 1);
    const int d = (idx >> 4) & (DINNER - 1);
    const int b = idx >> 15;

    const float Av = negA[d * DSTATE + n];
    const size_t hstride = (size_t)BATCH * DINNER * DSTATE;
    const size_t sstride = (size_t)BATCH * DINNER;
    const size_t ho0 = ((size_t)b * DINNER + d) * DSTATE + n;
    const size_t so0 = (size_t)b * DINNER + d;

    float hin = 0.f;
    for (int c0 = 0; c0 < NCHUNK; c0 += 8) {
        float e[8], dAc[8];
        #pragma unroll
        for (int k = 0; k < 8; ++k) {
            e[k]   = H[ho0 + (size_t)(c0 + k) * hstride];
            dAc[k] = Sdt[so0 + (size_t)(c0 + k) * sstride];
        }
        #pragma unroll
        for (int k = 0; k < 8; ++k) dAc[k] = fast_exp2(Av * dAc[k]);
        #pragma unroll
        for (int k = 0; k < 8; ++k) {
            H[ho0 + (size_t)(c0 + k) * hstride] = hin;
            hin = dAc[k] * hin + e[k];
        }
    }
}

// ---------------------------------------------------------------------------
// phase 3: redo chunk scan from Hin, emit y, fused ymod.
// R22: structured powers-of-w path (verified). Generic fallback kept.
// ---------------------------------------------------------------------------
__global__ __launch_bounds__(256) void scan_phase3(
    const ushort* __restrict__ delta, const ushort* __restrict__ u,
    const ushort* __restrict__ xdbl, const float* __restrict__ negA,
    const float* __restrict__ Hin, const float* __restrict__ Dp,
    const ushort* __restrict__ xr, ushort* __restrict__ yb,
    const int* __restrict__ sflag)
{
    const int idx = blockIdx.x * 256 + threadIdx.x;
    const int d = idx & (DINNER - 1);
    const int b = (idx >> 11) & (BATCH - 1);
    const int c = idx >> 12;
    const int strA = (sflag[1] == 0);

    float h[DSTATE];
    size_t ho = (((size_t)c * BATCH + b) * DINNER + d) * DSTATE;
    #pragma unroll
    for (int n = 0; n < DSTATE; n += 4) {
        floatx4 hv = *(const floatx4*)&Hin[ho + n];
        h[n] = hv[0]; h[n + 1] = hv[1]; h[n + 2] = hv[2]; h[n + 3] = hv[3];
    }

    const float Dpd = Dp[d];
    const int t0 = c * CHUNK;
    size_t bd = ((size_t)b * L_SEQ + t0) * DINNER + d;
    size_t bx = ((size_t)b * L_SEQ + t0) * 96 + DTRANK;
    size_t br = ((size_t)b * L_SEQ + t0) * (2 * DINNER) + DINNER + d;

    if (strA) {
        for (int t = 0; t < CHUNK; ++t) {
            float dt = bf2f(delta[bd]);
            float uv = bf2f(u[bd]);
            float du = dt * uv;
            short8 B0 = *(const short8*)&xdbl[bx];
            short8 B1 = *(const short8*)&xdbl[bx + 8];
            short8 C0 = *(const short8*)&xdbl[bx + 16];
            short8 C1 = *(const short8*)&xdbl[bx + 24];
            float w  = fast_exp2(-dt * LOG2E);        // exp(-dt)
            float w2 = w * w, w4 = w2 * w2, w8 = w4 * w4;
            float p3 = w2 * w, p5 = w4 * w, p6 = w4 * w2, p7 = w4 * p3;
            float dA[16] = {w, w2, p3, w4, p5, p6, p7, w8,
                            w8 * w, w8 * w2, w8 * p3, w8 * w4,
                            w8 * p5, w8 * p6, w8 * p7, w8 * w8};
            float y = 0.f;
            #pragma unroll
            for (int n = 0; n < 8; ++n) {
                h[n] = dA[n] * h[n] + du * bf2f((ushort)B0[n]);
                y += h[n] * bf2f((ushort)C0[n]);
            }
            #pragma unroll
            for (int n = 0; n < 8; ++n) {
                h[8 + n] = dA[8 + n] * h[8 + n] + du * bf2f((ushort)B1[n]);
                y += h[8 + n] * bf2f((ushort)C1[n]);
            }
            float yv = y + uv * Dpd;
            float r  = bf2f(xr[br]);
            yb[bd] = f2bf(yv * silu_f(r));
            bd += DINNER; bx += 96; br += 2 * DINNER;
        }
    } else {
        float Av[DSTATE];
        #pragma unroll
        for (int n = 0; n < DSTATE; ++n)
            Av[n] = negA[d * DSTATE + n];
        for (int t = 0; t < CHUNK; ++t) {
            float dt = bf2f(delta[bd]);
            float uv = bf2f(u[bd]);
            float du = dt * uv;
            short8 B0 = *(const short8*)&xdbl[bx];
            short8 B1 = *(const short8*)&xdbl[bx + 8];
            short8 C0 = *(const short8*)&xdbl[bx + 16];
            short8 C1 = *(const short8*)&xdbl[bx + 24];
            float y = 0.f;
            #pragma unroll
            for (int n = 0; n < 8; ++n) {
                h[n] = fast_exp2(dt * Av[n]) * h[n] + du * bf2f((ushort)B0[n]);
                y += h[n] * bf2f((ushort)C0[n]);
            }
            #pragma unroll
            for (int n = 0; n < 8; ++n) {
                h[8 + n] = fast_exp2(dt * Av[8 + n]) * h[8 + n] + du * bf2f((ushort)B1[n]);
                y += h[8 + n] * bf2f((ushort)C1[n]);
            }
            float yv = y + uv * Dpd;
            float r  = bf2f(xr[br]);
            yb[bd] = f2bf(yv * silu_f(r));
            bd += DINNER; bx += 96; br += 2 * DINNER;
        }
    }
}

// ---------------------------------------------------------------------------
extern "C" void kernel_launch(void* const* d_in, const int* in_sizes, int n_in,
                              void* d_out, int out_size, void* d_ws, size_t ws_size,
                              hipStream_t stream) {
    const void* x_raw      = d_in[0];
    const void* wqkv_raw   = d_in[1];
    const void* bqkv_raw   = d_in[2];
    const void* wao_raw    = d_in[3];
    const void* bao_raw    = d_in[4];
    const void* win_raw    = d_in[5];
    const void* convw_raw  = d_in[6];
    const void* convb_raw  = d_in[7];
    const void* wxp_raw    = d_in[8];
    const void* wdt_raw    = d_in[9];
    const void* bdt_raw    = d_in[10];
    const void* Alog_raw   = d_in[11];
    const void* Dp_raw     = d_in[12];
    const void* wout_raw   = d_in[13];

    const int M = BATCH * L_SEQ;  // 4096

    char* p = (char*)d_ws;
    size_t off = 0;
    auto A_ = [&](size_t bytes) { void* q = p + off; off += (bytes + 255) & ~255ull; return q; };

    ushort* x_b    = (ushort*)A_((size_t)M * NDIM * 2);
    ushort* wqkv_t = (ushort*)A_((size_t)NDIM * 1152 * 2);
    ushort* wao_t  = (ushort*)A_((size_t)NDIM * NDIM * 2);
    ushort* win_t  = (ushort*)A_((size_t)NDIM * 4096 * 2);
    float*  psum   = (float*)x_b;
    ushort* yb     = x_b;
    float*  Sdt    = (float*)(x_b + (size_t)M * DINNER);

    ushort* qkv    = (ushort*)A_((size_t)M * 1152 * 2);
    ushort* att    = (ushort*)A_((size_t)M * NDIM * 2);
    float*  Hend   = (float*)qkv;

    ushort* delta_b = (ushort*)A_((size_t)M * DINNER * 2);

    ushort* wxp_t  = (ushort*)A_((size_t)128 * DINNER * 2);
    ushort* wdt_t  = (ushort*)A_((size_t)DTRANK * DINNER * 2);
    ushort* wout_t = (ushort*)A_((size_t)DINNER * NDIM * 2);
    float*  bqkv_f = (float*)A_(1152 * 4);
    float*  bao_f  = (float*)A_(NDIM * 4);
    float*  convw_f= (float*)A_((size_t)DINNER * DCONV * 4);
    float*  convb_f= (float*)A_(DINNER * 4);
    float*  bdt_f  = (float*)A_(DINNER * 4);
    float*  Alog_f = (float*)A_((size_t)DINNER * DSTATE * 4);
    float*  Dp_f   = (float*)A_(DINNER * 4);
    int*    flag   = (int*)A_(256);
    ushort* x1b    = (ushort*)A_((size_t)M * NDIM * 2);
    ushort* xr     = (ushort*)A_((size_t)M * 4096 * 2);
    ushort* u      = (ushort*)A_((size_t)M * DINNER * 2);
    ushort* xdbl   = (ushort*)A_((size_t)M * 96 * 2);

    ushort* partO = xr;
    float*  partL = (float*)u;

    dim3 blk(256);

    // flag[0] = dtype (written by prep), flag[1] = A-structure mismatch count
    hipMemsetAsync(flag, 0, 8, stream);

    // 0. one-launch prep (probe + x cvt x8 + 6 transposes + pad + small params)
    prep_kernel<<<dim3(11137), blk, 0, stream>>>(
        x_raw, wqkv_raw, wao_raw, win_raw, wxp_raw, wdt_raw, wout_raw,
        bqkv_raw, bao_raw, convw_raw, convb_raw, bdt_raw, Alog_raw, Dp_raw,
        x_b, wqkv_t, wao_t, win_t, wxp_t, wdt_t, wout_t,
        bqkv_f, bao_f, convw_f, convb_f, bdt_f, Alog_f, Dp_f, flag);

    // 1. qkv = x @ wqkv + bqkv   (swap=0)
    gemm128<<<dim3(1152 / 128, M / 128), blk, 0, stream>>>(
        x_b, NDIM, wqkv_t, bqkv_f, nullptr, qkv, nullptr, nullptr, 1152, NDIM, 0, NDIM, nullptr, 0);

    // 2. flash attention (dense LPT 1D grid: 160 work entries x 8 hgb) + combine
    flash_attn_split<<<dim3(1280), blk, 0, stream>>>(
        qkv, att, partO, partL);
    attn_combine<<<dim3(1536), blk, 0, stream>>>(partO, partL, att);

    // 3. x1 = att @ w_ao + b_ao + x   (swap=0)
    gemm128<<<dim3(NDIM / 128, M / 128), blk, 0, stream>>>(
        att, NDIM, wao_t, bao_f, x_b, x1b, nullptr, nullptr, NDIM, NDIM, 0, NDIM, nullptr, 0);

    // 4. xr = x1 @ w_in   (swap=1: XCD-local A-strip)
    gemm128<<<dim3(M / 128, 4096 / 128), blk, 0, stream>>>(
        x1b, NDIM, win_t, nullptr, nullptr, xr, nullptr, nullptr, 4096, NDIM, 0, NDIM, nullptr, 1);

    // 5. conv + silu -> u  (1 channel/thread, 16 L/thread)
    conv_silu<<<dim3((M / 16) * (DINNER / 256)), blk, 0, stream>>>(xr, convw_f, convb_f, u);

    // 6. xdbl = u @ w_xproj  (split-K=8 over padded N=128)
    gemm128<<<dim3(1, M / 128, 8), blk, 0, stream>>>(
        u, DINNER, wxp_t, nullptr, nullptr, nullptr, nullptr, nullptr, 128, DINNER, 0, DINNER / 8, psum, 0);
    combine_xdbl<<<dim3(M * 96 / 256), blk, 0, stream>>>(psum, xdbl);

    // 7. delta = softplus(xdbl[:, :64] @ w_dt + b_dt)  (swap=0)
    gemm128<<<dim3(DINNER / 128, M / 128), blk, 0, stream>>>(
        xdbl, 96, wdt_t, bdt_f, nullptr, delta_b, nullptr, nullptr, DINNER, DTRANK, 1, DTRANK, nullptr, 0);

    // 8. chunked selective scan (+fused ymod) -> yb
    scan_phase1<<<dim3(NCHUNK * BATCH * DINNER * 2 / 256), blk, 0, stream>>>(
        delta_b, u, xdbl, Alog_f, Hend, Sdt, flag);
    scan_phase2<<<dim3(BATCH * DINNER * DSTATE / 256), blk, 0, stream>>>(
        Hend, Sdt, Alog_f);
    scan_phase3<<<dim3(NCHUNK * BATCH * DINNER / 256), blk, 0, stream>>>(
        delta_b, u, xdbl, Alog_f, Hend, Dp_f, xr, yb, flag);

    // 10. out = yb @ w_out + x1  (swap=1)
    gemm128<<<dim3(M / 128, NDIM / 128), blk, 0, stream>>>(
        yb, DINNER, wout_t, nullptr, x1b, (ushort*)d_out, (float*)d_out, flag, NDIM, DINNER, 0, DINNER, nullptr, 1);
}

// Round 14
// 393.355 us; speedup vs baseline: 1.0534x; 1.0136x over previous
//
#include <hip/hip_runtime.h>

#define L_SEQ   2048
#define BATCH   2
#define NDIM    1024
#define NHEADS  16
#define HD      64
#define DSTATE  16
#define DCONV   4
#define DINNER  2048
#define DTRANK  64
#define CHUNK   32
#define NCHUNK  (L_SEQ / CHUNK)   // 64
#define SPLIT_KT 8                // KV tiles (64) per attention split
#define LOG2E   1.4426950408889634f

typedef short  short8  __attribute__((ext_vector_type(8)));
typedef float  floatx4 __attribute__((ext_vector_type(4)));

#define AS1 __attribute__((address_space(1)))
#define AS3 __attribute__((address_space(3)))

__device__ __forceinline__ float bf2f(ushort u) {
    union { uint i; float f; } v; v.i = ((uint)u) << 16; return v.f;
}
#if defined(__has_builtin) && __has_builtin(__builtin_amdgcn_cvt_pk_bf16_f32)
__device__ __forceinline__ ushort f2bf(float f) {
    auto p = __builtin_amdgcn_cvt_pk_bf16_f32(f, f);
    union { decltype(p) v; ushort u[2]; } cv; cv.v = p;
    return cv.u[0];
}
__device__ __forceinline__ uint pk2bf(float lo, float hi) {
    auto p = __builtin_amdgcn_cvt_pk_bf16_f32(lo, hi);
    union { decltype(p) v; uint u; } cv; cv.v = p;
    return cv.u;
}
#else
__device__ __forceinline__ ushort f2bf(float f) {
    uint x = __float_as_uint(f);
    uint r = (x + 0x7fffu + ((x >> 16) & 1u)) >> 16;
    return (ushort)r;
}
__device__ __forceinline__ uint pk2bf(float lo, float hi) {
    return ((uint)f2bf(hi) << 16) | (uint)f2bf(lo);
}
#endif
#if defined(__has_builtin) && __has_builtin(__builtin_amdgcn_exp2f)
__device__ __forceinline__ float fast_exp2(float x) {
    return __builtin_amdgcn_exp2f(x);
}
#else
__device__ __forceinline__ float fast_exp2(float x) {
    return __expf(x * 0.6931471805599453f);
}
#endif
__device__ __forceinline__ float silu_f(float x) {
    return x / (1.f + __expf(-x));
}
__device__ __forceinline__ void gld_lds16(const void* g, void* l) {
    __builtin_amdgcn_global_load_lds((const AS1 uint*)g, (AS3 uint*)l, 16, 0, 0);
}
__device__ __forceinline__ float cvt_one(const void* s, int i, int f) {
    return f ? ((const float*)s)[i] : bf2f(((const ushort*)s)[i]);
}

// ---------------------------------------------------------------------------
// MEGA PREP (R21 negA2, R22 A-structure verify, R24 x-convert x8).
// ---------------------------------------------------------------------------
__global__ __launch_bounds__(256) void prep_kernel(
    const void* __restrict__ x_raw,
    const void* __restrict__ wqkv, const void* __restrict__ wao,
    const void* __restrict__ win,  const void* __restrict__ wxp,
    const void* __restrict__ wdt,  const void* __restrict__ wout,
    const void* __restrict__ bqkv, const void* __restrict__ bao,
    const void* __restrict__ convw, const void* __restrict__ convb,
    const void* __restrict__ bdt,  const void* __restrict__ Alog,
    const void* __restrict__ Dp,
    ushort* __restrict__ x_b, ushort* __restrict__ wqkv_t,
    ushort* __restrict__ wao_t, ushort* __restrict__ win_t,
    ushort* __restrict__ wxp_t, ushort* __restrict__ wdt_t,
    ushort* __restrict__ wout_t,
    float* __restrict__ bqkv_f, float* __restrict__ bao_f,
    float* __restrict__ convw_f, float* __restrict__ convb_f,
    float* __restrict__ bdt_f, float* __restrict__ Alog_f,
    float* __restrict__ Dp_f, int* __restrict__ flag)
{
    __shared__ int cnt;
    __shared__ float tile[32][33];
    if (threadIdx.x == 0) cnt = 0;
    __syncthreads();
    {
        ushort w = ((const ushort*)x_raw)[threadIdx.x];
        int e = (w >> 7) & 0xff;
        if (w != 0 && (e < 100 || e > 140)) atomicAdd(&cnt, 1);
    }
    __syncthreads();
    const int f = (cnt >= 16) ? 1 : 0;
    if (blockIdx.x == 0 && threadIdx.x == 0) *flag = f;

    int id = blockIdx.x;
    if (id < 2048) {                                // x convert, 8/thread
        int i = (id * 256 + threadIdx.x) * 8;
        if (f) {
            floatx4 a = *(const floatx4*)((const float*)x_raw + i);
            floatx4 c = *(const floatx4*)((const float*)x_raw + i + 4);
            short8 o;
            o[0] = (short)f2bf(a[0]); o[1] = (short)f2bf(a[1]);
            o[2] = (short)f2bf(a[2]); o[3] = (short)f2bf(a[3]);
            o[4] = (short)f2bf(c[0]); o[5] = (short)f2bf(c[1]);
            o[6] = (short)f2bf(c[2]); o[7] = (short)f2bf(c[3]);
            *(short8*)&x_b[i] = o;
        } else {
            *(short8*)&x_b[i] = *(const short8*)((const ushort*)x_raw + i);
        }
        return;
    }
    id -= 2048;

    const void* src = nullptr; ushort* dst = nullptr; int K = 0, N = 0;
    if (id < 1152)                     { src = wqkv; dst = wqkv_t; K = 1024; N = 1152; }
    else if ((id -= 1152) < 1024)      { src = wao;  dst = wao_t;  K = 1024; N = 1024; }
    else if ((id -= 1024) < 4096)      { src = win;  dst = win_t;  K = 1024; N = 4096; }
    else if ((id -= 4096) < 192)       { src = wxp;  dst = wxp_t;  K = 2048; N = 96;   }
    else if ((id -= 192)  < 128)       { src = wdt;  dst = wdt_t;  K = 64;   N = 2048; }
    else if ((id -= 128)  < 2048)      { src = wout; dst = wout_t; K = 2048; N = 1024; }
    else {
        id -= 2048;
        if (id < 256) {                              // wxp pad rows 96..127
            wxp_t[(size_t)96 * DINNER + id * 256 + threadIdx.x] = 0;
        } else {                                     // small params
            int i = (id - 256) * 256 + threadIdx.x;
            if      (i < 1152)   bqkv_f[i]          = cvt_one(bqkv,  i,          f);
            else if (i < 2176)   bao_f[i - 1152]    = cvt_one(bao,   i - 1152,   f);
            else if (i < 10368)  convw_f[i - 2176]  = cvt_one(convw, i - 2176,   f);
            else if (i < 12416)  convb_f[i - 10368] = cvt_one(convb, i - 10368,  f);
            else if (i < 14464)  bdt_f[i - 12416]   = cvt_one(bdt,   i - 12416,  f);
            else if (i < 47232) {
                int ai = i - 14464;
                float v = -__expf(cvt_one(Alog, ai, f)) * LOG2E;   // negA2
                Alog_f[ai] = v;
                int np1 = (ai & 15) + 1;
                float expv = -(float)np1 * LOG2E;
                if (fabsf(v - expv) > 1e-5f * (float)np1)
                    atomicAdd(flag + 1, 1);
            }
            else if (i < 49280)  Dp_f[i - 47232]    = cvt_one(Dp,    i - 47232,  f);
        }
        return;
    }

    const int ntn = N / 32;
    const int n0 = (id % ntn) * 32, k0 = (id / ntn) * 32;
    const int tx = threadIdx.x & 31, ty = threadIdx.x >> 5;
    #pragma unroll
    for (int r = 0; r < 4; ++r) {
        size_t o = (size_t)(k0 + ty + r * 8) * N + n0 + tx;
        tile[ty + r * 8][tx] = cvt_one(src, (int)o, f);
    }
    __syncthreads();
    #pragma unroll
    for (int r = 0; r < 4; ++r) {
        int n = n0 + ty + r * 8;
        dst[(size_t)n * K + k0 + tx] = f2bf(tile[tx][ty + r * 8]);
    }
}

// ---------------------------------------------------------------------------
// MFMA GEMM: 128x128 tile, BK=64, XOR k-slot swizzle.
// R17: bijective XCD swizzle + LDS-staged f32 epilogue.
// R19: 2-phase double-buffered staging.
// ---------------------------------------------------------------------------
__global__ __launch_bounds__(256) void gemm128(
    const ushort* __restrict__ A, int lda,
    const ushort* __restrict__ Wt,
    const float* __restrict__ bias,
    const ushort* __restrict__ resb,
    ushort* __restrict__ outb, float* __restrict__ outf,
    const int* __restrict__ dtflag,
    int N, int K, int act, int klen, float* __restrict__ psum, int swap)
{
    __shared__ __align__(16) char smem[65536];   // 2 x (As 16K + Bs 16K)

    const int tid  = threadIdx.x;
    const int wave = tid >> 6;
    const int lane = tid & 63;
    const int wm = (wave >> 1) * 64;
    const int wn = (wave & 1) * 64;
    const int fm = lane & 15;
    const int quad = lane >> 4;

    int bx = blockIdx.x, by = blockIdx.y;
    {
        const int gx = gridDim.x;
        const int nwg = gx * gridDim.y;
        const int id = by * gx + bx;
        const int qq = nwg >> 3;
        const int sid = (id & 7) * qq + (id >> 3);
        bx = sid % gx; by = sid / gx;
    }
    const int m0 = (swap ? bx : by) * 128;
    const int n0 = (swap ? by : bx) * 128;

    floatx4 acc[4][4];
    #pragma unroll
    for (int i = 0; i < 4; ++i)
        #pragma unroll
        for (int j = 0; j < 4; ++j) acc[i][j] = (floatx4){0.f, 0.f, 0.f, 0.f};

    int rowv[4], kgv[4];
    #pragma unroll
    for (int j = 0; j < 4; ++j) {
        int c = wave * 256 + j * 64 + lane;
        rowv[j] = c >> 3;
        kgv[j]  = (((c & 7) ^ ((c >> 3) & 7))) * 8;
    }

    const int kbeg = psum ? (blockIdx.z * klen) : 0;
    const int kend = kbeg + klen;

    auto stage = [&](int buf, int k0) {
        ushort* As = (ushort*)(smem + buf * 32768);
        ushort* Bs = (ushort*)(smem + buf * 32768 + 16384);
        #pragma unroll
        for (int j = 0; j < 4; ++j)
            gld_lds16(A  + (size_t)(m0 + rowv[j]) * lda + k0 + kgv[j],
                      &As[(wave * 256 + j * 64) * 8]);
        #pragma unroll
        for (int j = 0; j < 4; ++j)
            gld_lds16(Wt + (size_t)(n0 + rowv[j]) * K   + k0 + kgv[j],
                      &Bs[(wave * 256 + j * 64) * 8]);
    };

    stage(0, kbeg);
    __syncthreads();

    int cur = 0;
    for (int k0 = kbeg; k0 < kend; k0 += 64) {
        if (k0 + 64 < kend) stage(cur ^ 1, k0 + 64);
        const ushort* As = (const ushort*)(smem + cur * 32768);
        const ushort* Bs = (const ushort*)(smem + cur * 32768 + 16384);

        #pragma unroll
        for (int h = 0; h < 2; ++h) {
            short8 af[4], bf[4];
            #pragma unroll
            for (int i = 0; i < 4; ++i) {
                int row = wm + i * 16 + fm;
                int slot = (h * 4 + quad) ^ (row & 7);
                af[i] = *(const short8*)&As[row * 64 + slot * 8];
            }
            #pragma unroll
            for (int j = 0; j < 4; ++j) {
                int row = wn + j * 16 + fm;
                int slot = (h * 4 + quad) ^ (row & 7);
                bf[j] = *(const short8*)&Bs[row * 64 + slot * 8];
            }
            #pragma unroll
            for (int i = 0; i < 4; ++i)
                #pragma unroll
                for (int j = 0; j < 4; ++j)
                    acc[i][j] = __builtin_amdgcn_mfma_f32_16x16x32_bf16(af[i], bf[j], acc[i][j], 0, 0, 0);
        }
        __syncthreads();
        cur ^= 1;
    }

    if (psum) {
        int mgrid = swap ? gridDim.x : gridDim.y;
        float* po = psum + (size_t)blockIdx.z * ((size_t)mgrid * 128) * N;
        #pragma unroll
        for (int j = 0; j < 4; ++j) {
            int col = n0 + wn + j * 16 + fm;
            #pragma unroll
            for (int i = 0; i < 4; ++i) {
                int rowb = m0 + wm + i * 16 + quad * 4;
                #pragma unroll
                for (int r = 0; r < 4; ++r)
                    po[(size_t)(rowb + r) * N + col] = acc[i][j][r];
            }
        }
        return;
    }

    const int flagv = dtflag ? *dtflag : 0;
    const bool wf = dtflag ? (flagv != 0) : (outf != nullptr);
    float* Cs = (float*)smem;               // [64][132] f32
    const int lrw = (wm >> 1) + quad * 4;
    #pragma unroll
    for (int p = 0; p < 2; ++p) {
        #pragma unroll
        for (int ih = 0; ih < 2; ++ih) {
            const int i = 2 * p + ih;
            #pragma unroll
            for (int j = 0; j < 4; ++j) {
                float bvv = bias ? bias[n0 + wn + j * 16 + fm] : 0.f;
                #pragma unroll
                for (int r = 0; r < 4; ++r) {
                    float v = acc[i][j][r] + bvv;
                    if (act == 1)
                        v = fmaxf(v, 0.f) + __logf(1.f + __expf(-fabsf(v)));
                    Cs[(lrw + ih * 16 + r) * 132 + wn + j * 16 + fm] = v;
                }
            }
        }
        __syncthreads();
        #pragma unroll
        for (int g = 0; g < 4; ++g) {
            const int lr   = g * 16 + (tid >> 4);
            const int colc = (tid & 15) * 8;
            const int grow = m0 + (lr >> 5) * 64 + (2 * p + ((lr >> 4) & 1)) * 16 + (lr & 15);
            const size_t o = (size_t)grow * N + n0 + colc;
            floatx4 v0 = *(const floatx4*)&Cs[lr * 132 + colc];
            floatx4 v1 = *(const floatx4*)&Cs[lr * 132 + colc + 4];
            float vv[8] = {v0[0], v0[1], v0[2], v0[3], v1[0], v1[1], v1[2], v1[3]};
            if (resb) {
                short8 rs = *(const short8*)&resb[o];
                #pragma unroll
                for (int k = 0; k < 8; ++k) vv[k] += bf2f((ushort)rs[k]);
            }
            if (wf) {
                *(floatx4*)&outf[o]     = (floatx4){vv[0], vv[1], vv[2], vv[3]};
                *(floatx4*)&outf[o + 4] = (floatx4){vv[4], vv[5], vv[6], vv[7]};
            } else {
                short8 ov;
                #pragma unroll
                for (int k = 0; k < 8; ++k) ov[k] = (short)f2bf(vv[k]);
                *(short8*)&outb[o] = ov;
            }
        }
        __syncthreads();
    }
}

// ---------------------------------------------------------------------------
// combine split-K partials -> xdbl bf16 (stride 96).
// ---------------------------------------------------------------------------
__global__ __launch_bounds__(256) void combine_xdbl(
    const float* __restrict__ psum, ushort* __restrict__ xdbl)
{
    int idx = blockIdx.x * 256 + threadIdx.x;
    int row = idx / 96, col = idx - row * 96;
    float s = 0.f;
    #pragma unroll
    for (int z = 0; z < 8; ++z)
        s += psum[(size_t)z * 4096 * 128 + row * 128 + col];
    xdbl[idx] = f2bf(s);
}

// ---------------------------------------------------------------------------
// Flash MQA attention, split-KV, static-max softmax.
// R16: swapped QK^T + in-register bpermute P exchange. R18: dense LPT grid.
// R25 KVBLK=128: stage 128 KV rows per barrier pair (4 reg passes), then
// run the 64-kv compute body twice against the two LDS halves. Barriers
// per 512-kv split: 16 -> 8. Odd tail stages a masked extra tile (unused
// half; reads stay inside workspace). LDS 18.4 -> 36.9 KB.
// ---------------------------------------------------------------------------
__global__ __launch_bounds__(256) void flash_attn_split(
    const ushort* __restrict__ qkv, ushort* __restrict__ att,
    ushort* __restrict__ partO, float* __restrict__ partL)
{
    __shared__ __align__(16) ushort Ks[128 * 72];
    __shared__ __align__(16) ushort Vt[128 * 72];

    // ---- R18 dense LPT decode ----
    const int id  = blockIdx.x;
    const int e   = id >> 3;
    const int hgb = id & 7;
    const int hg  = hgb >> 1;
    const int b   = hgb & 1;
    int tile, s;
    if (e < 104) {
        if      (e < 50)  { s = 0; tile = 63 - e; }
        else if (e < 84)  { s = 1; tile = 63 - (e - 50); }
        else if (e < 102) { s = 2; tile = 63 - (e - 84); }
        else              { s = 3; tile = 63 - (e - 102); }
    } else {
        const int rem = e - 104;
        const int w   = 7 - (rem >> 3);
        s    = (rem & 7) >> 1;
        tile = 2 * (8 * s + w) - 2 + (rem & 1);
    }

    const int q0 = tile * 32;
    const int nkv = (q0 >> 6) + 1;
    const int nsplit = (nkv + SPLIT_KT - 1) / SPLIT_KT;
    const int kt0 = s * SPLIT_KT;
    const int kt1 = (nkv < kt0 + SPLIT_KT) ? nkv : (kt0 + SPLIT_KT);

    const int tid  = threadIdx.x;
    const int wave = tid >> 6;
    const int lane = tid & 63;
    const int fm   = lane & 15;
    const int quad = lane >> 4;
    const int h    = hg * 4 + wave;

    const int srow = tid >> 3;
    const int scol = (tid & 7) * 8;
    const int vsw  = (tid & 7) << 3;

    const int addrA = (fm + (quad & 1) * 32) * 4;
    const int addrB = addrA + 64;
    const bool jlo_sel = (quad < 2);

    short8 qf[2][2];
    #pragma unroll
    for (int i = 0; i < 2; ++i)
        #pragma unroll
        for (int kh = 0; kh < 2; ++kh)
            qf[i][kh] = *(const short8*)(qkv +
                (size_t)(b * L_SEQ + q0 + i * 16 + fm) * 1152 + h * HD + kh * 32 + quad * 8);

    floatx4 acc[2][4];
    float l_lane[2];
    #pragma unroll
    for (int i = 0; i < 2; ++i) {
        #pragma unroll
        for (int j = 0; j < 4; ++j) acc[i][j] = (floatx4){0.f, 0.f, 0.f, 0.f};
        l_lane[i] = 0.f;
    }

    // 128-row register staging (2 KV tiles per barrier pair)
    short8 kreg[4], vreg[4];
    auto loadkv = [&](int ktp) {
        const int kv0 = ktp * 64;
        #pragma unroll
        for (int pass = 0; pass < 4; ++pass) {
            int row = srow + pass * 32;
            const ushort* kp = qkv + (size_t)(b * L_SEQ + kv0 + row) * 1152 + NDIM + scol;
            kreg[pass] = *(const short8*)kp;
            vreg[pass] = *(const short8*)(kp + HD);
        }
    };
    auto stage128 = [&]() {
        #pragma unroll
        for (int pass = 0; pass < 4; ++pass) {
            int row = srow + pass * 32;          // 0..127
            *(short8*)&Ks[row * 72 + scol] = kreg[pass];
            int rh = row >> 6, rl = row & 63;
            int mw = rl ^ vsw;
            #pragma unroll
            for (int i2 = 0; i2 < 8; ++i2)
                Vt[rh * 64 * 72 + (scol + i2) * 72 + mw] = (ushort)vreg[pass][i2];
        }
    };

    // 64-kv compute body against LDS half at 'off'
    auto body = [&](int kt) {
        const int kv0 = kt * 64;
        const int off = (kt & 1) * 64 * 72;
        floatx4 spT[4][2];
        __builtin_amdgcn_s_setprio(1);
        #pragma unroll
        for (int j = 0; j < 4; ++j) {
            short8 kf0 = *(const short8*)&Ks[off + (j * 16 + fm) * 72 + quad * 8];
            short8 kf1 = *(const short8*)&Ks[off + (j * 16 + fm) * 72 + 32 + quad * 8];
            #pragma unroll
            for (int i = 0; i < 2; ++i) {
                floatx4 z = (floatx4){0.f, 0.f, 0.f, 0.f};
                z = __builtin_amdgcn_mfma_f32_16x16x32_bf16(kf0, qf[i][0], z, 0, 0, 0);
                z = __builtin_amdgcn_mfma_f32_16x16x32_bf16(kf1, qf[i][1], z, 0, 0, 0);
                spT[j][i] = z;
            }
        }
        __builtin_amdgcn_s_setprio(0);

        const bool diag = (kt == nkv - 1);
        #pragma unroll
        for (int j = 0; j < 4; ++j)
            #pragma unroll
            for (int i = 0; i < 2; ++i) {
                #pragma unroll
                for (int r = 0; r < 4; ++r) {
                    float p = fast_exp2(spT[j][i][r] * 0.18033688011112042f);
                    if (diag) {
                        int kvg = kv0 + j * 16 + quad * 4 + r;
                        int qg  = q0 + i * 16 + fm;
                        if (kvg > qg) p = 0.f;
                    }
                    spT[j][i][r] = p;
                    l_lane[i] += p;
                }
            }

        uint w0[4][2], w1[4][2];
        #pragma unroll
        for (int j = 0; j < 4; ++j)
            #pragma unroll
            for (int i = 0; i < 2; ++i) {
                w0[j][i] = pk2bf(spT[j][i][0], spT[j][i][1]);
                w1[j][i] = pk2bf(spT[j][i][2], spT[j][i][3]);
            }

        short8 pf[2][2];
        #pragma unroll
        for (int i = 0; i < 2; ++i)
            #pragma unroll
            for (int kh = 0; kh < 2; ++kh) {
                const int jl = kh * 2, jh = kh * 2 + 1;
                uint a0 = (uint)__builtin_amdgcn_ds_bpermute(addrA, (int)w0[jl][i]);
                uint a1 = (uint)__builtin_amdgcn_ds_bpermute(addrA, (int)w0[jh][i]);
                uint b0 = (uint)__builtin_amdgcn_ds_bpermute(addrA, (int)w1[jl][i]);
                uint b1 = (uint)__builtin_amdgcn_ds_bpermute(addrA, (int)w1[jh][i]);
                uint c0 = (uint)__builtin_amdgcn_ds_bpermute(addrB, (int)w0[jl][i]);
                uint c1 = (uint)__builtin_amdgcn_ds_bpermute(addrB, (int)w0[jh][i]);
                uint d0 = (uint)__builtin_amdgcn_ds_bpermute(addrB, (int)w1[jl][i]);
                uint d1 = (uint)__builtin_amdgcn_ds_bpermute(addrB, (int)w1[jh][i]);
                union { uint u[4]; short8 s; } cv;
                cv.u[0] = jlo_sel ? a0 : a1;
                cv.u[1] = jlo_sel ? b0 : b1;
                cv.u[2] = jlo_sel ? c0 : c1;
                cv.u[3] = jlo_sel ? d0 : d1;
                pf[i][kh] = cv.s;
            }

        __builtin_amdgcn_s_setprio(1);
        #pragma unroll
        for (int dj = 0; dj < 4; ++dj) {
            int d = dj * 16 + fm;
            int sw8 = ((d >> 3) & 7) << 3;
            short8 vf0 = *(const short8*)&Vt[off + d * 72 + ((quad * 8) ^ sw8)];
            short8 vf1 = *(const short8*)&Vt[off + d * 72 + ((32 + quad * 8) ^ sw8)];
            #pragma unroll
            for (int i = 0; i < 2; ++i) {
                acc[i][dj] = __builtin_amdgcn_mfma_f32_16x16x32_bf16(pf[i][0], vf0, acc[i][dj], 0, 0, 0);
                acc[i][dj] = __builtin_amdgcn_mfma_f32_16x16x32_bf16(pf[i][1], vf1, acc[i][dj], 0, 0, 0);
            }
        }
        __builtin_amdgcn_s_setprio(0);
    };

    // main loop over 128-row pairs
    loadkv(kt0);
    for (int ktp = kt0; ktp < kt1; ktp += 2) {
        __syncthreads();
        stage128();
        __syncthreads();
        if (ktp + 2 < kt1) loadkv(ktp + 2);
        body(ktp);
        if (ktp + 1 < kt1) body(ktp + 1);
    }

    #pragma unroll
    for (int i = 0; i < 2; ++i) {
        float rs = l_lane[i];
        rs += __shfl_xor(rs, 16);
        rs += __shfl_xor(rs, 32);
        l_lane[i] = rs;
    }

    if (nsplit == 1) {
        #pragma unroll
        for (int i = 0; i < 2; ++i) {
            float inv[4];
            #pragma unroll
            for (int r = 0; r < 4; ++r)
                inv[r] = 1.f / __shfl(l_lane[i], quad * 4 + r, 16);
            #pragma unroll
            for (int dj = 0; dj < 4; ++dj)
                #pragma unroll
                for (int r = 0; r < 4; ++r) {
                    int q = q0 + i * 16 + quad * 4 + r;
                    att[(size_t)(b * L_SEQ + q) * NDIM + h * HD + dj * 16 + fm] =
                        f2bf(acc[i][dj][r] * inv[r]);
                }
        }
    } else {
        size_t pbase = ((size_t)((s * 2 + b) * 16 + h)) * L_SEQ;
        #pragma unroll
        for (int i = 0; i < 2; ++i)
            #pragma unroll
            for (int dj = 0; dj < 4; ++dj)
                #pragma unroll
                for (int r = 0; r < 4; ++r) {
                    int q = q0 + i * 16 + quad * 4 + r;
                    partO[(pbase + q) * 64 + dj * 16 + fm] = f2bf(acc[i][dj][r]);
                }
        if (lane < 16) {
            #pragma unroll
            for (int i = 0; i < 2; ++i)
                partL[pbase + q0 + i * 16 + fm] = l_lane[i];
        }
    }
}

// ---------------------------------------------------------------------------
// combine attention split partials for q >= 512.
// ---------------------------------------------------------------------------
__global__ __launch_bounds__(256) void attn_combine(
    const ushort* __restrict__ partO, const float* __restrict__ partL,
    ushort* __restrict__ att)
{
    int gid = blockIdx.x * 256 + threadIdx.x;
    int t8 = gid & 7;
    int row = gid >> 3;
    int q  = 512 + (row % 1536);
    int bh = row / 1536;
    int b = bh >> 4, h = bh & 15;
    int nsplit = (((q >> 5) >> 1) + 1 + SPLIT_KT - 1) / SPLIT_KT;

    float sum[8] = {0.f, 0.f, 0.f, 0.f, 0.f, 0.f, 0.f, 0.f};
    float L = 0.f;
    for (int s = 0; s < nsplit; ++s) {
        size_t pbase = ((size_t)((s * 2 + b) * 16 + h)) * L_SEQ + q;
        L += partL[pbase];
        short8 o = *(const short8*)&partO[pbase * 64 + t8 * 8];
        #pragma unroll
        for (int k = 0; k < 8; ++k) sum[k] += bf2f((ushort)o[k]);
    }
    float inv = 1.f / L;
    short8 outv;
    #pragma unroll
    for (int k = 0; k < 8; ++k) outv[k] = (short)f2bf(sum[k] * inv);
    *(short8*)&att[((size_t)(b * L_SEQ + q)) * NDIM + h * HD + t8 * 8] = outv;
}

// ---------------------------------------------------------------------------
// depthwise conv (window 4, left pad 3) + bias + silu. (R15)
// ---------------------------------------------------------------------------
__global__ __launch_bounds__(256) void conv_silu(
    const ushort* __restrict__ xr, const float* __restrict__ conv_w,
    const float* __restrict__ conv_b, ushort* __restrict__ u)
{
    const int c   = ((blockIdx.x & 7) << 8) + threadIdx.x;  // 0..2047
    const int bl0 = (blockIdx.x >> 3) << 4;                 // 0..4080 step 16
    const int l0  = bl0 & (L_SEQ - 1);                      // pos within batch

    const floatx4 wv = *(const floatx4*)&conv_w[c * DCONV];
    const float bias = conv_b[c];

    float xv[19];
    #pragma unroll
    for (int t = 0; t < 19; ++t) {
        int ls = l0 - 3 + t;
        xv[t] = (ls >= 0)
              ? bf2f(xr[(size_t)(bl0 - 3 + t) * (2 * DINNER) + c])
              : 0.f;
    }

    #pragma unroll
    for (int t = 0; t < 16; ++t) {
        float a = bias + xv[t] * wv[0] + xv[t + 1] * wv[1]
                       + xv[t + 2] * wv[2] + xv[t + 3] * wv[3];
        u[(size_t)(bl0 + t) * DINNER + c] = f2bf(silu_f(a));
    }
}

// ---------------------------------------------------------------------------
// Chunked selective scan, phase 1 (R20 half-split, R22 powers-of-w).
// ---------------------------------------------------------------------------
__global__ __launch_bounds__(256) void scan_phase1(
    const ushort* __restrict__ delta, const ushort* __restrict__ u,
    const ushort* __restrict__ xdbl, const float* __restrict__ negA,
    float* __restrict__ Hend, float* __restrict__ Sdt,
    const int* __restrict__ sflag)
{
    const int idx  = blockIdx.x * 256 + threadIdx.x;
    const int lane = idx & 63;
    const int g    = idx >> 6;
    const int half = lane >> 5;
    const int d    = ((g & 63) << 5) + (lane & 31);
    const int b    = (g >> 6) & (BATCH - 1);
    const int c    = g >> 7;
    const int strA = (sflag[1] == 0);

    float h[8];
    #pragma unroll
    for (int n = 0; n < 8; ++n) h[n] = 0.f;

    const int t0 = c * CHUNK;
    size_t bd = ((size_t)b * L_SEQ + t0) * DINNER + d;
    size_t bx = ((size_t)b * L_SEQ + t0) * 96 + DTRANK + half * 8;
    float sdt = 0.f;

    if (strA) {
        for (int t = 0; t < CHUNK; ++t) {
            float dt = bf2f(delta[bd]);
            float uv = bf2f(u[bd]);
            sdt += dt;
            float du = dt * uv;
            short8 B0 = *(const short8*)&xdbl[bx];
            float w  = fast_exp2(-dt * LOG2E);
            float w2 = w * w, w4 = w2 * w2, w8 = w4 * w4;
            float p3 = w2 * w;
            float q[8] = {w, w2, p3, w4, w4 * w, w4 * w2, w4 * p3, w8};
            float sc = half ? w8 : 1.f;
            #pragma unroll
            for (int n = 0; n < 8; ++n)
                h[n] = (q[n] * sc) * h[n] + du * bf2f((ushort)B0[n]);
            bd += DINNER; bx += 96;
        }
    } else {
        float Av[8];
        #pragma unroll
        for (int n = 0; n < 8; ++n)
            Av[n] = negA[d * DSTATE + half * 8 + n];
        for (int t = 0; t < CHUNK; ++t) {
            float dt = bf2f(delta[bd]);
            float uv = bf2f(u[bd]);
            sdt += dt;
            float du = dt * uv;
            short8 B0 = *(const short8*)&xdbl[bx];
            #pragma unroll
            for (int n = 0; n < 8; ++n)
                h[n] = fast_exp2(dt * Av[n]) * h[n] + du * bf2f((ushort)B0[n]);
            bd += DINNER; bx += 96;
        }
    }

    size_t ho = (((size_t)c * BATCH + b) * DINNER + d) * DSTATE + half * 8;
    *(floatx4*)&Hend[ho]     = (floatx4){h[0], h[1], h[2], h[3]};
    *(floatx4*)&Hend[ho + 4] = (floatx4){h[4], h[5], h[6], h[7]};
    if (half == 0)
        Sdt[((size_t)c * BATCH + b) * DINNER + d] = sdt;
}

// ---------------------------------------------------------------------------
// phase 2: in-place exclusive combine over 64 chunks (R19 batched).
// ---------------------------------------------------------------------------
__global__ __launch_bounds__(256) void scan_phase2(
    float* __restrict__ H, const float* __restrict__ Sdt,
    const float* __restrict__ negA)
{
    const int idx = blockIdx.x * 256 + threadIdx.x;
    const int n = idx & (DSTATE - 1);
    const int d = (idx >> 4) & (DINNER - 1);
    const int b = idx >> 15;

    const float Av = negA[d * DSTATE + n];
    const size_t hstride = (size_t)BATCH * DINNER * DSTATE;
    const size_t sstride = (size_t)BATCH * DINNER;
    const size_t ho0 = ((size_t)b * DINNER + d) * DSTATE + n;
    const size_t so0 = (size_t)b * DINNER + d;

    float hin = 0.f;
    for (int c0 = 0; c0 < NCHUNK; c0 += 8) {
        float e[8], dAc[8];
        #pragma unroll
        for (int k = 0; k < 8; ++k) {
            e[k]   = H[ho0 + (size_t)(c0 + k) * hstride];
            dAc[k] = Sdt[so0 + (size_t)(c0 + k) * sstride];
        }
        #pragma unroll
        for (int k = 0; k < 8; ++k) dAc[k] = fast_exp2(Av * dAc[k]);
        #pragma unroll
        for (int k = 0; k < 8; ++k) {
            H[ho0 + (size_t)(c0 + k) * hstride] = hin;
            hin = dAc[k] * hin + e[k];
        }
    }
}

// ---------------------------------------------------------------------------
// phase 3: redo chunk scan from Hin, emit y, fused ymod (R22 powers-of-w).
// ---------------------------------------------------------------------------
__global__ __launch_bounds__(256) void scan_phase3(
    const ushort* __restrict__ delta, const ushort* __restrict__ u,
    const ushort* __restrict__ xdbl, const float* __restrict__ negA,
    const float* __restrict__ Hin, const float* __restrict__ Dp,
    const ushort* __restrict__ xr, ushort* __restrict__ yb,
    const int* __restrict__ sflag)
{
    const int idx = blockIdx.x * 256 + threadIdx.x;
    const int d = idx & (DINNER - 1);
    const int b = (idx >> 11) & (BATCH - 1);
    const int c = idx >> 12;
    const int strA = (sflag[1] == 0);

    float h[DSTATE];
    size_t ho = (((size_t)c * BATCH + b) * DINNER + d) * DSTATE;
    #pragma unroll
    for (int n = 0; n < DSTATE; n += 4) {
        floatx4 hv = *(const floatx4*)&Hin[ho + n];
        h[n] = hv[0]; h[n + 1] = hv[1]; h[n + 2] = hv[2]; h[n + 3] = hv[3];
    }

    const float Dpd = Dp[d];
    const int t0 = c * CHUNK;
    size_t bd = ((size_t)b * L_SEQ + t0) * DINNER + d;
    size_t bx = ((size_t)b * L_SEQ + t0) * 96 + DTRANK;
    size_t br = ((size_t)b * L_SEQ + t0) * (2 * DINNER) + DINNER + d;

    if (strA) {
        for (int t = 0; t < CHUNK; ++t) {
            float dt = bf2f(delta[bd]);
            float uv = bf2f(u[bd]);
            float du = dt * uv;
            short8 B0 = *(const short8*)&xdbl[bx];
            short8 B1 = *(const short8*)&xdbl[bx + 8];
            short8 C0 = *(const short8*)&xdbl[bx + 16];
            short8 C1 = *(const short8*)&xdbl[bx + 24];
            float w  = fast_exp2(-dt * LOG2E);
            float w2 = w * w, w4 = w2 * w2, w8 = w4 * w4;
            float p3 = w2 * w, p5 = w4 * w, p6 = w4 * w2, p7 = w4 * p3;
            float dA[16] = {w, w2, p3, w4, p5, p6, p7, w8,
                            w8 * w, w8 * w2, w8 * p3, w8 * w4,
                            w8 * p5, w8 * p6, w8 * p7, w8 * w8};
            float y = 0.f;
            #pragma unroll
            for (int n = 0; n < 8; ++n) {
                h[n] = dA[n] * h[n] + du * bf2f((ushort)B0[n]);
                y += h[n] * bf2f((ushort)C0[n]);
            }
            #pragma unroll
            for (int n = 0; n < 8; ++n) {
                h[8 + n] = dA[8 + n] * h[8 + n] + du * bf2f((ushort)B1[n]);
                y += h[8 + n] * bf2f((ushort)C1[n]);
            }
            float yv = y + uv * Dpd;
            float r  = bf2f(xr[br]);
            yb[bd] = f2bf(yv * silu_f(r));
            bd += DINNER; bx += 96; br += 2 * DINNER;
        }
    } else {
        float Av[DSTATE];
        #pragma unroll
        for (int n = 0; n < DSTATE; ++n)
            Av[n] = negA[d * DSTATE + n];
        for (int t = 0; t < CHUNK; ++t) {
            float dt = bf2f(delta[bd]);
            float uv = bf2f(u[bd]);
            float du = dt * uv;
            short8 B0 = *(const short8*)&xdbl[bx];
            short8 B1 = *(const short8*)&xdbl[bx + 8];
            short8 C0 = *(const short8*)&xdbl[bx + 16];
            short8 C1 = *(const short8*)&xdbl[bx + 24];
            float y = 0.f;
            #pragma unroll
            for (int n = 0; n < 8; ++n) {
                h[n] = fast_exp2(dt * Av[n]) * h[n] + du * bf2f((ushort)B0[n]);
                y += h[n] * bf2f((ushort)C0[n]);
            }
            #pragma unroll
            for (int n = 0; n < 8; ++n) {
                h[8 + n] = fast_exp2(dt * Av[8 + n]) * h[8 + n] + du * bf2f((ushort)B1[n]);
                y += h[8 + n] * bf2f((ushort)C1[n]);
            }
            float yv = y + uv * Dpd;
            float r  = bf2f(xr[br]);
            yb[bd] = f2bf(yv * silu_f(r));
            bd += DINNER; bx += 96; br += 2 * DINNER;
        }
    }
}

// ---------------------------------------------------------------------------
extern "C" void kernel_launch(void* const* d_in, const int* in_sizes, int n_in,
                              void* d_out, int out_size, void* d_ws, size_t ws_size,
                              hipStream_t stream) {
    const void* x_raw      = d_in[0];
    const void* wqkv_raw   = d_in[1];
    const void* bqkv_raw   = d_in[2];
    const void* wao_raw    = d_in[3];
    const void* bao_raw    = d_in[4];
    const void* win_raw    = d_in[5];
    const void* convw_raw  = d_in[6];
    const void* convb_raw  = d_in[7];
    const void* wxp_raw    = d_in[8];
    const void* wdt_raw    = d_in[9];
    const void* bdt_raw    = d_in[10];
    const void* Alog_raw   = d_in[11];
    const void* Dp_raw     = d_in[12];
    const void* wout_raw   = d_in[13];

    const int M = BATCH * L_SEQ;  // 4096

    char* p = (char*)d_ws;
    size_t off = 0;
    auto A_ = [&](size_t bytes) { void* q = p + off; off += (bytes + 255) & ~255ull; return q; };

    ushort* x_b    = (ushort*)A_((size_t)M * NDIM * 2);
    ushort* wqkv_t = (ushort*)A_((size_t)NDIM * 1152 * 2);
    ushort* wao_t  = (ushort*)A_((size_t)NDIM * NDIM * 2);
    ushort* win_t  = (ushort*)A_((size_t)NDIM * 4096 * 2);
    float*  psum   = (float*)x_b;
    ushort* yb     = x_b;
    float*  Sdt    = (float*)(x_b + (size_t)M * DINNER);

    ushort* qkv    = (ushort*)A_((size_t)M * 1152 * 2);
    ushort* att    = (ushort*)A_((size_t)M * NDIM * 2);
    float*  Hend   = (float*)qkv;

    ushort* delta_b = (ushort*)A_((size_t)M * DINNER * 2);

    ushort* wxp_t  = (ushort*)A_((size_t)128 * DINNER * 2);
    ushort* wdt_t  = (ushort*)A_((size_t)DTRANK * DINNER * 2);
    ushort* wout_t = (ushort*)A_((size_t)DINNER * NDIM * 2);
    float*  bqkv_f = (float*)A_(1152 * 4);
    float*  bao_f  = (float*)A_(NDIM * 4);
    float*  convw_f= (float*)A_((size_t)DINNER * DCONV * 4);
    float*  convb_f= (float*)A_(DINNER * 4);
    float*  bdt_f  = (float*)A_(DINNER * 4);
    float*  Alog_f = (float*)A_((size_t)DINNER * DSTATE * 4);
    float*  Dp_f   = (float*)A_(DINNER * 4);
    int*    flag   = (int*)A_(256);
    ushort* x1b    = (ushort*)A_((size_t)M * NDIM * 2);
    ushort* xr     = (ushort*)A_((size_t)M * 4096 * 2);
    ushort* u      = (ushort*)A_((size_t)M * DINNER * 2);
    ushort* xdbl   = (ushort*)A_((size_t)M * 96 * 2);

    ushort* partO = xr;
    float*  partL = (float*)u;

    dim3 blk(256);

    // flag[0] = dtype (written by prep), flag[1] = A-structure mismatch count
    hipMemsetAsync(flag, 0, 8, stream);

    // 0. one-launch prep
    prep_kernel<<<dim3(11137), blk, 0, stream>>>(
        x_raw, wqkv_raw, wao_raw, win_raw, wxp_raw, wdt_raw, wout_raw,
        bqkv_raw, bao_raw, convw_raw, convb_raw, bdt_raw, Alog_raw, Dp_raw,
        x_b, wqkv_t, wao_t, win_t, wxp_t, wdt_t, wout_t,
        bqkv_f, bao_f, convw_f, convb_f, bdt_f, Alog_f, Dp_f, flag);

    // 1. qkv = x @ wqkv + bqkv
    gemm128<<<dim3(1152 / 128, M / 128), blk, 0, stream>>>(
        x_b, NDIM, wqkv_t, bqkv_f, nullptr, qkv, nullptr, nullptr, 1152, NDIM, 0, NDIM, nullptr, 0);

    // 2. flash attention (dense LPT grid; KVBLK=128) + combine
    flash_attn_split<<<dim3(1280), blk, 0, stream>>>(
        qkv, att, partO, partL);
    attn_combine<<<dim3(1536), blk, 0, stream>>>(partO, partL, att);

    // 3. x1 = att @ w_ao + b_ao + x
    gemm128<<<dim3(NDIM / 128, M / 128), blk, 0, stream>>>(
        att, NDIM, wao_t, bao_f, x_b, x1b, nullptr, nullptr, NDIM, NDIM, 0, NDIM, nullptr, 0);

    // 4. xr = x1 @ w_in
    gemm128<<<dim3(M / 128, 4096 / 128), blk, 0, stream>>>(
        x1b, NDIM, win_t, nullptr, nullptr, xr, nullptr, nullptr, 4096, NDIM, 0, NDIM, nullptr, 1);

    // 5. conv + silu -> u
    conv_silu<<<dim3((M / 16) * (DINNER / 256)), blk, 0, stream>>>(xr, convw_f, convb_f, u);

    // 6. xdbl = u @ w_xproj (split-K=8)
    gemm128<<<dim3(1, M / 128, 8), blk, 0, stream>>>(
        u, DINNER, wxp_t, nullptr, nullptr, nullptr, nullptr, nullptr, 128, DINNER, 0, DINNER / 8, psum, 0);
    combine_xdbl<<<dim3(M * 96 / 256), blk, 0, stream>>>(psum, xdbl);

    // 7. delta = softplus(xdbl[:, :64] @ w_dt + b_dt)
    gemm128<<<dim3(DINNER / 128, M / 128), blk, 0, stream>>>(
        xdbl, 96, wdt_t, bdt_f, nullptr, delta_b, nullptr, nullptr, DINNER, DTRANK, 1, DTRANK, nullptr, 0);

    // 8. chunked selective scan
    scan_phase1<<<dim3(NCHUNK * BATCH * DINNER * 2 / 256), blk, 0, stream>>>(
        delta_b, u, xdbl, Alog_f, Hend, Sdt, flag);
    scan_phase2<<<dim3(BATCH * DINNER * DSTATE / 256), blk, 0, stream>>>(
        Hend, Sdt, Alog_f);
    scan_phase3<<<dim3(NCHUNK * BATCH * DINNER / 256), blk, 0, stream>>>(
        delta_b, u, xdbl, Alog_f, Hend, Dp_f, xr, yb, flag);

    // 10. out = yb @ w_out + x1
    gemm128<<<dim3(M / 128, NDIM / 128), blk, 0, stream>>>(
        yb, DINNER, wout_t, nullptr, x1b, (ushort*)d_out, (float*)d_out, flag, NDIM, DINNER, 0, DINNER, nullptr, 1);
}